// Round 10
// baseline (447.601 us; speedup 1.0000x reference)
//
#include <hip/hip_runtime.h>

typedef unsigned short u16;
typedef unsigned int u32;
typedef __attribute__((ext_vector_type(8))) short bf16x8;   // 8 bf16 = 4 VGPR
typedef __attribute__((ext_vector_type(4))) float f32x4;

#define MFMA16(d, a, bb) d = __builtin_amdgcn_mfma_f32_16x16x32_bf16(a, bb, d, 0, 0, 0)

// padded image geometry: [b][130][130][512], 1-px zero border
#define PROW 130
#define PIMG 16900              // 130*130 pixels
#define PIMGC (16900 * 512)     // u16 per image

__device__ __forceinline__ u16 f2bf(float f){
  union { float f; u32 i; } v; v.f = f;
  u32 r = v.i + 0x7fffu + ((v.i >> 16) & 1u);
  return (u16)(r >> 16);
}

// async global->LDS, 16B per lane; LDS dest = wave-uniform base + lane*16
__device__ __forceinline__ void gl16(const u16* g, u16* l){
  __builtin_amdgcn_global_load_lds(
      (const __attribute__((address_space(1))) u32*)g,
      (__attribute__((address_space(3))) u32*)l, 16, 0, 0);
}

// ---------------------------------------------------------------------------
// zero the 1-px border of a padded [2][130][130][512] buffer
__global__ __launch_bounds__(256) void k_border(u16* __restrict__ buf){
  const int b = blockIdx.y;
  const int j = blockIdx.x * 4 + (threadIdx.x >> 6);   // 0..515
  const int l = threadIdx.x & 63;
  int pp;
  if(j < 130)       pp = j;                      // top row
  else if(j < 260)  pp = 129 * 130 + (j - 130);  // bottom row
  else if(j < 388)  pp = (j - 259) * 130;        // left col rows 1..128
  else              pp = (j - 387) * 130 + 129;  // right col rows 1..128
  u16* p = buf + ((size_t)b * PIMG + pp) * 512 + l * 8;
  *(uint4*)p = (uint4){0u, 0u, 0u, 0u};
}

// x: fp32 [256][16384] -> FUSEDP padded [pix][ch] bf16, ch 0..255
__global__ __launch_bounds__(256) void k_transpose_pad(const float* __restrict__ in,
                                                       u16* __restrict__ out){
  __shared__ float s[32][33];
  const float* ip = in + (size_t)blockIdx.z * 256 * 16384;
  u16* op = out + (size_t)blockIdx.z * PIMGC;
  int r0 = blockIdx.x * 32, c0 = blockIdx.y * 32;
  int tx = threadIdx.x, ty = threadIdx.y;
#pragma unroll
  for(int i = 0; i < 4; ++i){
    int r = ty * 4 + i;
    s[r][tx] = ip[(size_t)(r0 + r) * 16384 + (c0 + tx)];
  }
  __syncthreads();
#pragma unroll
  for(int i = 0; i < 4; ++i){
    int pix = c0 + ty * 4 + i;
    u32 pp = ((u32)(pix >> 7) + 1) * PROW + (pix & 127) + 1;
    op[(size_t)pp * 512 + (r0 + tx)] = f2bf(s[tx][ty * 4 + i]);
  }
}

// generic fp32 [rows][cols] -> bf16 [cols][rows] (used for xs -> XST)
__global__ __launch_bounds__(256) void k_transpose(const float* __restrict__ in,
                                                   u16* __restrict__ out,
                                                   int rows, int cols,
                                                   int ostride, size_t o_imgstride){
  __shared__ float s[32][33];
  const float* ip = in + (size_t)blockIdx.z * (size_t)rows * (size_t)cols;
  u16* op = out + (size_t)blockIdx.z * o_imgstride;
  int r0 = blockIdx.x * 32, c0 = blockIdx.y * 32;
  int tx = threadIdx.x, ty = threadIdx.y;
#pragma unroll
  for(int i = 0; i < 4; ++i){
    int r = ty * 4 + i;
    s[r][tx] = ip[(size_t)(r0 + r) * cols + (c0 + tx)];
  }
  __syncthreads();
#pragma unroll
  for(int i = 0; i < 4; ++i){
    int c = ty * 4 + i;
    op[(size_t)(c0 + c) * ostride + (r0 + tx)] = f2bf(s[tx][c]);
  }
}

// weights: [co][ci][3][3] f32 -> [e][co*co_mul+co_off][ci] bf16
__global__ __launch_bounds__(256) void k_wt(const float* __restrict__ in,
                                            u16* __restrict__ out,
                                            int co_mul, int co_off, int co_tot){
  int ci = blockIdx.x * 256 + threadIdx.x;   // 0..511
  int co = blockIdx.y;                       // 0..255
  int e  = blockIdx.z;                       // 0..8
  out[((size_t)e * co_tot + co * co_mul + co_off) * 512 + ci] =
      f2bf(in[((size_t)co * 512 + ci) * 9 + e]);
}

// ---------------------------------------------------------------------------
// scores8 MFMA: S8p[g][b][q=256][k=1280] partials, K-split over 8 tap-groups.
__global__ __launch_bounds__(256) void k_scores8(const u16* __restrict__ FUSEDP,
                                                 const u16* __restrict__ XST,
                                                 float* __restrict__ S8p){
  __shared__ u16 As[4096], Bs[4096];
  const int bz = blockIdx.z, b = bz >> 3, g = bz & 7;
  const int q0 = blockIdx.x * 128, k0 = blockIdx.y * 128;
  const int tid = threadIdx.x, w = tid >> 6, l = tid & 63;
  const int wr = w >> 1, wc = w & 1;
  const int l15 = l & 15, kg = (l >> 4) * 8;
  f32x4 acc[4][4];
#pragma unroll
  for(int m = 0; m < 4; ++m)
#pragma unroll
    for(int n = 0; n < 4; ++n) acc[m][n] = (f32x4){0.f, 0.f, 0.f, 0.f};

  for(int e8 = 0; e8 < 8; ++e8){
    const int e = g * 8 + e8, dy = e >> 3, dx = e & 7;
    for(int ci0 = 0; ci0 < 256; ci0 += 32){
#pragma unroll
      for(int r = 0; r < 2; ++r){
        const int idx = (w * 2 + r) * 64 + l;
        const int q = q0 + (idx >> 2);
        const int apy = ((q >> 4) << 3) + dy, apx = ((q & 15) << 3) + dx;
        const size_t pa = ((size_t)b * PIMG + (size_t)(apy + 1) * PROW + apx + 1) * 512
                          + ci0 + (idx & 3) * 8;
        gl16(FUSEDP + pa, As + (size_t)(w * 2 + r) * 512);
        const int k = k0 + (idx >> 2), t = k >> 8, rm = k & 255;
        const size_t pb = (((size_t)b * 5 + t) * 16384 +
                           (size_t)(((rm >> 4) << 3) + dy) * 128 + ((rm & 15) << 3) + dx) * 256
                          + ci0 + (idx & 3) * 8;
        gl16(XST + pb, Bs + (size_t)(w * 2 + r) * 512);
      }
      __syncthreads();
      bf16x8 af[4], bq[4];
#pragma unroll
      for(int m = 0; m < 4; ++m) af[m] = *(const bf16x8*)(As + (wr * 64 + m * 16 + l15) * 32 + kg);
#pragma unroll
      for(int n = 0; n < 4; ++n) bq[n] = *(const bf16x8*)(Bs + (wc * 64 + n * 16 + l15) * 32 + kg);
#pragma unroll
      for(int m = 0; m < 4; ++m)
#pragma unroll
        for(int n = 0; n < 4; ++n)
          acc[m][n] = __builtin_amdgcn_mfma_f32_16x16x32_bf16(af[m], bq[n], acc[m][n], 0, 0, 0);
      __syncthreads();
    }
  }
  float* dst = S8p + ((size_t)g * 2 + b) * 256 * 1280;
#pragma unroll
  for(int m = 0; m < 4; ++m){
    const int q = q0 + wr * 64 + m * 16 + (l >> 4) * 4;
#pragma unroll
    for(int n = 0; n < 4; ++n){
      const int k = k0 + wc * 64 + n * 16 + l15;
#pragma unroll
      for(int r = 0; r < 4; ++r) dst[(size_t)(q + r) * 1280 + k] = acc[m][n][r];
    }
  }
}

// softmax over k(1280), scale 1/128; sums 8 partials; writes A8 bf16.
__global__ __launch_bounds__(256) void k_softmax8(const float* __restrict__ S8p,
                                                  u16* __restrict__ A8){
  __shared__ float red[8];
  int b = blockIdx.x >> 8, q = blockIdx.x & 255;
  size_t roff = ((size_t)b * 256 + q) * 1280;
  int tid = threadIdx.x;
  float v[5]; float m = -1e30f;
#pragma unroll
  for(int i = 0; i < 5; ++i){
    size_t o = roff + tid + 256 * i;
    float s = 0.f;
#pragma unroll
    for(int g = 0; g < 8; ++g) s += S8p[(size_t)g * 655360 + o];
    v[i] = s * 0.0078125f; m = fmaxf(m, v[i]);
  }
#pragma unroll
  for(int o = 32; o > 0; o >>= 1) m = fmaxf(m, __shfl_xor(m, o));
  int wid = tid >> 6;
  if((tid & 63) == 0) red[wid] = m;
  __syncthreads();
  m = fmaxf(fmaxf(red[0], red[1]), fmaxf(red[2], red[3]));
  float s = 0.f;
#pragma unroll
  for(int i = 0; i < 5; ++i){ v[i] = __expf(v[i] - m); s += v[i]; }
#pragma unroll
  for(int o = 32; o > 0; o >>= 1) s += __shfl_xor(s, o);
  if((tid & 63) == 0) red[4 + wid] = s;
  __syncthreads();
  s = red[4] + red[5] + red[6] + red[7];
  float inv = 1.0f / s;
#pragma unroll
  for(int i = 0; i < 5; ++i) A8[roff + tid + 256 * i] = f2bf(v[i] * inv);
}

// scores16 from S8p quadrants, softmax over 320, scale 1/256 -> A16 bf16.
__global__ __launch_bounds__(320) void k_s16(const float* __restrict__ S8p,
                                             u16* __restrict__ A16){
  __shared__ float red[10];
  int b = blockIdx.x >> 6, q16 = blockIdx.x & 63;
  int tid = threadIdx.x;               // k16 in 0..319
  int t = tid >> 6, rm = tid & 63;
  int KY = rm >> 3, KX = rm & 7;
  int QY = q16 >> 3, QX = q16 & 7;
  float s = 0.f;
#pragma unroll
  for(int i = 0; i < 2; ++i)
#pragma unroll
    for(int j = 0; j < 2; ++j){
      int q8 = (2 * QY + i) * 16 + (2 * QX + j);
      int k8 = t * 256 + (2 * KY + i) * 16 + (2 * KX + j);
      size_t o = ((size_t)b * 256 + q8) * 1280 + k8;
#pragma unroll
      for(int g = 0; g < 8; ++g) s += S8p[(size_t)g * 655360 + o];
    }
  s *= 0.00390625f; // 1/256
  float m = s;
#pragma unroll
  for(int o = 32; o > 0; o >>= 1) m = fmaxf(m, __shfl_xor(m, o));
  int wid = tid >> 6;
  if((tid & 63) == 0) red[wid] = m;
  __syncthreads();
  m = fmaxf(fmaxf(fmaxf(red[0], red[1]), fmaxf(red[2], red[3])), red[4]);
  float e = __expf(s - m);
  float sm = e;
#pragma unroll
  for(int o = 32; o > 0; o >>= 1) sm += __shfl_xor(sm, o);
  if((tid & 63) == 0) red[5 + wid] = sm;
  __syncthreads();
  sm = red[5] + red[6] + red[7] + red[8] + red[9];
  A16[((size_t)b * 64 + q16) * 320 + tid] = f2bf(e / sm);
}

// ---------------------------------------------------------------------------
// val8 MFMA: per (b,ry,rx): OUT[q=256][ch=256] = A8[q][1280] @ Gt[ch][1280].
__global__ __launch_bounds__(256) void k_val8(const u16* __restrict__ A8,
                                              const u16* __restrict__ XST,
                                              u16* __restrict__ OUTCATP){
  __shared__ u16 As[4096];
  __shared__ u16 Bs[128 * 40];
  const int z = blockIdx.z, b = z >> 6, rr = z & 63;
  const int ry = rr >> 3, rx = rr & 7;
  const int q0 = blockIdx.x * 128, c0 = blockIdx.y * 128;
  const int tid = threadIdx.x, w = tid >> 6, l = tid & 63;
  const int wr = w >> 1, wc = w & 1;
  const int l15 = l & 15, kg = (l >> 4) * 8;
  const int k2 = tid >> 4, ch8 = tid & 15;   // B staging chunk
  f32x4 acc[4][4];
#pragma unroll
  for(int m = 0; m < 4; ++m)
#pragma unroll
    for(int n = 0; n < 4; ++n) acc[m][n] = (f32x4){0.f, 0.f, 0.f, 0.f};

  for(int k0 = 0; k0 < 1280; k0 += 32){
#pragma unroll
    for(int r = 0; r < 2; ++r){
      const int idx = (w * 2 + r) * 64 + l;
      const u16* ga = A8 + ((size_t)b * 256 + q0 + (idx >> 2)) * 1280 + k0 + (idx & 3) * 8;
      gl16(ga, As + (size_t)(w * 2 + r) * 512);
    }
    {
      const int ka = k0 + k2 * 2, kb = ka + 1;
      const int ta = ka >> 8, ra = ka & 255;
      const int tb = kb >> 8, rb = kb & 255;
      const size_t pa = (((size_t)b * 5 + ta) * 16384 +
                         (size_t)(((ra >> 4) << 3) + ry) * 128 + ((ra & 15) << 3) + rx) * 256
                        + c0 + ch8 * 8;
      const size_t pb = (((size_t)b * 5 + tb) * 16384 +
                         (size_t)(((rb >> 4) << 3) + ry) * 128 + ((rb & 15) << 3) + rx) * 256
                        + c0 + ch8 * 8;
      union { uint4 v; u16 s[8]; } u0, u1;
      u0.v = *(const uint4*)(XST + pa);
      u1.v = *(const uint4*)(XST + pb);
      const int kloc = k2 * 2, swz = (ch8 & 3) << 3;
#pragma unroll
      for(int j = 0; j < 8; ++j){
        u32 pack = (u32)u0.s[j] | ((u32)u1.s[j] << 16);
        *(u32*)(Bs + (size_t)(ch8 * 8 + j) * 40 + (kloc ^ swz)) = pack;
      }
    }
    __syncthreads();
    bf16x8 af[4], bq[4];
#pragma unroll
    for(int m = 0; m < 4; ++m) af[m] = *(const bf16x8*)(As + (wr * 64 + m * 16 + l15) * 32 + kg);
#pragma unroll
    for(int n = 0; n < 4; ++n){
      const int ch = wc * 64 + n * 16 + l15;
      bq[n] = *(const bf16x8*)(Bs + (size_t)ch * 40 + (kg ^ (((ch >> 3) & 3) << 3)));
    }
#pragma unroll
    for(int m = 0; m < 4; ++m)
#pragma unroll
      for(int n = 0; n < 4; ++n)
        acc[m][n] = __builtin_amdgcn_mfma_f32_16x16x32_bf16(af[m], bq[n], acc[m][n], 0, 0, 0);
    __syncthreads();
  }
#pragma unroll
  for(int m = 0; m < 4; ++m){
    const int qb = q0 + wr * 64 + m * 16 + (l >> 4) * 4;
#pragma unroll
    for(int n = 0; n < 4; ++n){
      const int ch = c0 + wc * 64 + n * 16 + l15;
#pragma unroll
      for(int r = 0; r < 4; ++r){
        const int q = qb + r;
        const int py = ((q >> 4) << 3) + ry, px = ((q & 15) << 3) + rx;
        OUTCATP[((size_t)b * PIMG + (size_t)(py + 1) * PROW + px + 1) * 512 + ch] = f2bf(acc[m][n][r]);
      }
    }
  }
}

// val16 MFMA (val8-clone, M=64, K=320): OUT[q=64][ch=128per-block] per
// (b,ry16,rx16) -> OUTCATP ch 256..511. A16 bf16 [b][64][320].
__global__ __launch_bounds__(256) void k_val16(const u16* __restrict__ A16,
                                               const u16* __restrict__ XST,
                                               u16* __restrict__ OUTCATP){
  __shared__ u16 As[64 * 32];
  __shared__ u16 Bs[128 * 40];
  const int z = blockIdx.z, b = z >> 8, rr = z & 255;
  const int ry = rr >> 4, rx = rr & 15;
  const int c0 = blockIdx.y * 128;
  const int tid = threadIdx.x, w = tid >> 6, l = tid & 63;
  const int l15 = l & 15, kg = (l >> 4) * 8;
  const int k2 = tid >> 4, ch8 = tid & 15;
  f32x4 acc[4][2];
#pragma unroll
  for(int m = 0; m < 4; ++m)
#pragma unroll
    for(int n = 0; n < 2; ++n) acc[m][n] = (f32x4){0.f, 0.f, 0.f, 0.f};

  for(int k0 = 0; k0 < 320; k0 += 32){
    {
      const int idx = w * 64 + l;
      const u16* ga = A16 + ((size_t)b * 64 + (idx >> 2)) * 320 + k0 + (idx & 3) * 8;
      gl16(ga, As + (size_t)w * 512);
    }
    {
      const int ka = k0 + k2 * 2, kb = ka + 1;
      const int ta = ka >> 6, ra = ka & 63;
      const int tb = kb >> 6, rb = kb & 63;
      const size_t pa = (((size_t)b * 5 + ta) * 16384 +
                         (size_t)(((ra >> 3) << 4) + ry) * 128 + ((ra & 7) << 4) + rx) * 256
                        + c0 + ch8 * 8;
      const size_t pb = (((size_t)b * 5 + tb) * 16384 +
                         (size_t)(((rb >> 3) << 4) + ry) * 128 + ((rb & 7) << 4) + rx) * 256
                        + c0 + ch8 * 8;
      union { uint4 v; u16 s[8]; } u0, u1;
      u0.v = *(const uint4*)(XST + pa);
      u1.v = *(const uint4*)(XST + pb);
      const int kloc = k2 * 2, swz = (ch8 & 3) << 3;
#pragma unroll
      for(int j = 0; j < 8; ++j){
        u32 pack = (u32)u0.s[j] | ((u32)u1.s[j] << 16);
        *(u32*)(Bs + (size_t)(ch8 * 8 + j) * 40 + (kloc ^ swz)) = pack;
      }
    }
    __syncthreads();
    bf16x8 af[4], bq[2];
#pragma unroll
    for(int m = 0; m < 4; ++m) af[m] = *(const bf16x8*)(As + (m * 16 + l15) * 32 + kg);
#pragma unroll
    for(int n = 0; n < 2; ++n){
      const int ch = w * 32 + n * 16 + l15;
      bq[n] = *(const bf16x8*)(Bs + (size_t)ch * 40 + (kg ^ (((ch >> 3) & 3) << 3)));
    }
#pragma unroll
    for(int m = 0; m < 4; ++m)
#pragma unroll
      for(int n = 0; n < 2; ++n)
        acc[m][n] = __builtin_amdgcn_mfma_f32_16x16x32_bf16(af[m], bq[n], acc[m][n], 0, 0, 0);
    __syncthreads();
  }
#pragma unroll
  for(int m = 0; m < 4; ++m){
    const int qb = m * 16 + (l >> 4) * 4;
#pragma unroll
    for(int n = 0; n < 2; ++n){
      const int ch = c0 + w * 32 + n * 16 + l15;
#pragma unroll
      for(int r = 0; r < 4; ++r){
        const int q = qb + r;
        const int py = ((q >> 3) << 4) + ry, px = ((q & 7) << 4) + rx;
        OUTCATP[((size_t)b * PIMG + (size_t)(py + 1) * PROW + px + 1) * 512 + 256 + ch] = f2bf(acc[m][n][r]);
      }
    }
  }
}

// ---------------------------------------------------------------------------
// swizzle for 64-byte LDS rows (BK=32): 2-way-max bank aliasing (free, m136)
__device__ __forceinline__ int swz32(int row){
  return ((row ^ (row >> 2)) & 3) << 4;
}

// Conv implicit-GEMM, occupancy-first v2: BK=32, per-wave 64xBNw output,
// 2 blocks/CU (LDS 48/32 KiB, acc<=64 VGPR, launch_bounds(512,4)).
// ci-major K-order: kt -> g=kt/18, sub=kt%18, e=sub%9, ci0=g*64+(sub/9)*32.
// 2-barrier loop + counted vmcnt; T2-style swizzle; T5 setprio.
// BN=256 (MODE1, gate/feat interleaved -> d_out) or 128 (MODE0, lin -> FUSEDP).
template<int MODE>
__global__ __launch_bounds__(512, 4) void k_conv32(const u16* __restrict__ A,
                                                   const u16* __restrict__ W,
                                                   const float* __restrict__ bias,
                                                   const float* __restrict__ bias2,
                                                   void* __restrict__ outp){
  constexpr int NT   = 144;                  // 8 ci-blocks * 18 (9 taps * 2 halves)
  constexpr int BN   = (MODE == 0) ? 128 : 256;
  constexpr int NF   = BN / 64;              // bq frags per wave (2 or 4)
  constexpr int NTOT = (MODE == 0) ? 256 : 512;
  constexpr int BJ   = BN / 128;             // B gl16 per thread per tile
  constexpr int BUFU = (128 + BN) * 32;      // u16 per buffer (64B rows)
  __shared__ u16 lds[2][BUFU];
  const int id = blockIdx.x;                     // 512 blocks
  const int wg = (id & 7) * 64 + (id >> 3);      // XCD-contiguous (512 = 8*64)
  const int ntile = wg >> 8;
  const int mm = wg & 255, b = mm >> 7, mt = mm & 127;
  const int m0 = mt * 128, n0 = ntile * BN;
  const int tid = threadIdx.x, w = tid >> 6, l = tid & 63;
  const int wr = w >> 2, wc = w & 3;             // 2 x 4 waves -> per-wave 64 x BN/4
  const int l15 = l & 15, lq = l >> 4;

  // per-lane staging constants: row-in-chunk (l>>2), col (l&3)*16 ^ swz
  const int srow = l >> 2;
  const u32 lanec = (u32)((((l & 3) * 16) ^ swz32(srow)) >> 1);

  u32 aB, bB[BJ];
  {
    const int row = w * 16 + srow;               // A rows: wave w covers 16 rows
    const int p = m0 + row;
    aB = ((u32)b * PIMG + ((u32)(p >> 7) + 1) * PROW + (u32)(p & 127) + 1) * 512 + lanec;
#pragma unroll
    for(int j = 0; j < BJ; ++j){
      const int rowb = (w * BJ + j) * 16 + srow; // B rows: 8*BJ chunks of 16
      bB[j] = (u32)(n0 + rowb) * 512 + lanec;
    }
  }

  f32x4 acc[4][NF];
#pragma unroll
  for(int m = 0; m < 4; ++m)
#pragma unroll
    for(int n = 0; n < NF; ++n) acc[m][n] = (f32x4){0.f, 0.f, 0.f, 0.f};

  auto STAGE = [&](int kt){
    const int g = kt / 18, sub = kt % 18;
    const int e = sub % 9, ci0 = g * 64 + (sub / 9) * 32;
    const int dy = e / 3 - 1, dx = e % 3 - 1;
    const int aD = (dy * PROW + dx) * 512 + ci0;
    const u32 bD = (u32)e * NTOT * 512u + ci0;
    u16* bufA = &lds[kt & 1][0];
    u16* bufB = &lds[kt & 1][4096];              // A = 128*32 u16 = 4096
    gl16(A + aB + aD, bufA + w * 512);
#pragma unroll
    for(int j = 0; j < BJ; ++j)
      gl16(W + bB[j] + bD, bufB + (w * BJ + j) * 512);
  };

  STAGE(0);
  STAGE(1);

  for(int t = 0; t < NT; ++t){
    if(t < NT - 1) asm volatile("s_waitcnt vmcnt(%0)" :: "i"(1 + BJ) : "memory");
    else           asm volatile("s_waitcnt vmcnt(0)" ::: "memory");
    __builtin_amdgcn_s_barrier();                  // buf[t&1] data visible
    const char* bufA = (const char*)&lds[t & 1][0];
    const char* bufB = bufA + 8192;
    bf16x8 af[4], bq[NF];
#pragma unroll
    for(int m = 0; m < 4; ++m){
      const int row = wr * 64 + m * 16 + l15;
      af[m] = *(const bf16x8*)(bufA + row * 64 + ((lq * 16) ^ swz32(row)));
    }
#pragma unroll
    for(int n = 0; n < NF; ++n){
      const int row = wc * (BN / 4) + n * 16 + l15;
      bq[n] = *(const bf16x8*)(bufB + row * 64 + ((lq * 16) ^ swz32(row)));
    }
    asm volatile("s_waitcnt lgkmcnt(0)" ::: "memory");
    __builtin_amdgcn_sched_barrier(0);
    __builtin_amdgcn_s_barrier();                  // all waves done reading buf[t&1]
    if(t + 2 < NT) STAGE(t + 2);                   // refill just-freed buffer
    __builtin_amdgcn_s_setprio(1);
#pragma unroll
    for(int m = 0; m < 4; ++m)
#pragma unroll
      for(int n = 0; n < NF; ++n)
        MFMA16(acc[m][n], af[m], bq[n]);
    __builtin_amdgcn_s_setprio(0);
  }

  if(MODE == 0){
    u16* ob = (u16*)outp;
#pragma unroll
    for(int m = 0; m < 4; ++m){
      const int p0 = m0 + wr * 64 + m * 16 + lq * 4;
      const size_t pp = ((size_t)b * PIMG + (size_t)((p0 >> 7) + 1) * PROW + (p0 & 127) + 1) * 512;
#pragma unroll
      for(int n = 0; n < NF; ++n){
        const int co = n0 + wc * 32 + n * 16 + l15;
        const float bi = bias[co];
#pragma unroll
        for(int r = 0; r < 4; ++r){
          float v = acc[m][n][r] + bi;
          v = v > 0.f ? v : 0.2f * v;
          ob[pp + (size_t)r * 512 + 256 + co] = f2bf(v);
        }
      }
    }
  } else {
    float* ob = (float*)outp;
#pragma unroll
    for(int m = 0; m < 4; ++m){
      const int p0 = m0 + wr * 64 + m * 16 + lq * 4;
#pragma unroll
      for(int n = 0; n < NF; ++n){
        const int col = n0 + wc * 64 + n * 16 + l15;
        const int s = col & 1, co = col >> 1;
        const float big = bias[co], bif = bias2[co];
        float res[4];
#pragma unroll
        for(int r = 0; r < 4; ++r){
          const float val = acc[m][n][r];
          const float oth = __shfl_xor(val, 1);
          float gg = s ? oth : val;
          float ff = s ? val : oth;
          gg += big; ff += bif;
          ff = ff > 0.f ? ff : 0.2f * ff;
          res[r] = ff / (1.0f + __expf(-gg));
        }
        if(s == 0){
          float4 v4 = make_float4(res[0], res[1], res[2], res[3]);
          *(float4*)&ob[((size_t)b * 256 + co) * 16384 + p0] = v4;
        }
      }
    }
  }
}

// ---------------------------------------------------------------------------
extern "C" void kernel_launch(void* const* d_in, const int* in_sizes, int n_in,
                              void* d_out, int out_size, void* d_ws, size_t ws_size,
                              hipStream_t stream){
  const float* x      = (const float*)d_in[0];
  const float* xs     = (const float*)d_in[1];
  // d_in[2] = ms : unused (mask is a no-op in the reference)
  const float* w_lin  = (const float*)d_in[3];
  const float* b_lin  = (const float*)d_in[4];
  const float* w_gate = (const float*)d_in[5];
  const float* b_gate = (const float*)d_in[6];
  const float* w_feat = (const float*)d_in[7];
  const float* b_feat = (const float*)d_in[8];
  float* out = (float*)d_out;

  char* ws = (char*)d_ws;
  size_t off = 0;
  auto alloc = [&](size_t bytes) -> void* {
    void* p = ws + off;
    off += (bytes + 255) & ~(size_t)255;
    return p;
  };
  u16* FUSEDP  = (u16*)alloc(2ull * PIMGC * 2);       // padded [b][130][130][512]
  u16* OUTCATP = (u16*)alloc(2ull * PIMGC * 2);       // padded [b][130][130][512]
  u16* XST     = (u16*)alloc(10ull * 16384 * 256 * 2);// xs NHWC bf16
  u16* WTl     = (u16*)alloc(9ull * 256 * 512 * 2);   // [e][co][ci]
  u16* WGF     = (u16*)alloc(9ull * 512 * 512 * 2);   // [e][2co+s][ci]
  float* S8p   = (float*)alloc(8ull * 655360 * 4);    // [g][b][256][1280]
  u16* A8      = (u16*)alloc(655360ull * 2);          // bf16 [b][256][1280]
  u16* A16     = (u16*)alloc(2ull * 64 * 320 * 2);    // bf16 [b][64][320]

  // zero padded borders (interior written by producers)
  k_border<<<dim3(129, 2), 256, 0, stream>>>(FUSEDP);
  k_border<<<dim3(129, 2), 256, 0, stream>>>(OUTCATP);

  dim3 tb(32, 8);
  k_transpose_pad<<<dim3(8, 512, 2), tb, 0, stream>>>(x, FUSEDP);
  k_transpose<<<dim3(8, 512, 10), tb, 0, stream>>>(xs, XST, 256, 16384, 256, 4194304ull);

  k_wt<<<dim3(2, 256, 9), 256, 0, stream>>>(w_lin,  WTl, 1, 0, 256);
  k_wt<<<dim3(2, 256, 9), 256, 0, stream>>>(w_gate, WGF, 2, 0, 512);
  k_wt<<<dim3(2, 256, 9), 256, 0, stream>>>(w_feat, WGF, 2, 1, 512);

  k_scores8<<<dim3(2, 10, 16), 256, 0, stream>>>(FUSEDP, XST, S8p);
  k_softmax8<<<512, 256, 0, stream>>>(S8p, A8);
  k_s16<<<128, 320, 0, stream>>>(S8p, A16);

  k_val8 <<<dim3(2, 2, 128), 256, 0, stream>>>(A8, XST, OUTCATP);
  k_val16<<<dim3(1, 2, 512), 256, 0, stream>>>(A16, XST, OUTCATP);

  k_conv32<0><<<512, 512, 0, stream>>>(OUTCATP, WTl, b_lin, nullptr, (void*)FUSEDP);
  k_conv32<1><<<512, 512, 0, stream>>>(FUSEDP, WGF, b_gate, b_feat, (void*)out);
}

// Round 11
// 405.183 us; speedup vs baseline: 1.1047x; 1.1047x over previous
//
#include <hip/hip_runtime.h>

typedef unsigned short u16;
typedef unsigned int u32;
typedef __attribute__((ext_vector_type(8))) short bf16x8;   // 8 bf16 = 4 VGPR
typedef __attribute__((ext_vector_type(4))) float f32x4;

#define MFMA16(d, a, bb) d = __builtin_amdgcn_mfma_f32_16x16x32_bf16(a, bb, d, 0, 0, 0)

// padded image geometry: [b][130][130][512], 1-px zero border
#define PROW 130
#define PIMG 16900              // 130*130 pixels
#define PIMGC (16900 * 512)     // u16 per image

__device__ __forceinline__ u16 f2bf(float f){
  union { float f; u32 i; } v; v.f = f;
  u32 r = v.i + 0x7fffu + ((v.i >> 16) & 1u);
  return (u16)(r >> 16);
}

// async global->LDS, 16B per lane; LDS dest = wave-uniform base + lane*16
__device__ __forceinline__ void gl16(const u16* g, u16* l){
  __builtin_amdgcn_global_load_lds(
      (const __attribute__((address_space(1))) u32*)g,
      (__attribute__((address_space(3))) u32*)l, 16, 0, 0);
}

// ---------------------------------------------------------------------------
// zero the 1-px border of a padded [2][130][130][512] buffer
__global__ __launch_bounds__(256) void k_border(u16* __restrict__ buf){
  const int b = blockIdx.y;
  const int j = blockIdx.x * 4 + (threadIdx.x >> 6);   // 0..515
  const int l = threadIdx.x & 63;
  int pp;
  if(j < 130)       pp = j;                      // top row
  else if(j < 260)  pp = 129 * 130 + (j - 130);  // bottom row
  else if(j < 388)  pp = (j - 259) * 130;        // left col rows 1..128
  else              pp = (j - 387) * 130 + 129;  // right col rows 1..128
  u16* p = buf + ((size_t)b * PIMG + pp) * 512 + l * 8;
  *(uint4*)p = (uint4){0u, 0u, 0u, 0u};
}

// x: fp32 [256][16384] -> FUSEDP padded [pix][ch] bf16, ch 0..255
__global__ __launch_bounds__(256) void k_transpose_pad(const float* __restrict__ in,
                                                       u16* __restrict__ out){
  __shared__ float s[32][33];
  const float* ip = in + (size_t)blockIdx.z * 256 * 16384;
  u16* op = out + (size_t)blockIdx.z * PIMGC;
  int r0 = blockIdx.x * 32, c0 = blockIdx.y * 32;
  int tx = threadIdx.x, ty = threadIdx.y;
#pragma unroll
  for(int i = 0; i < 4; ++i){
    int r = ty * 4 + i;
    s[r][tx] = ip[(size_t)(r0 + r) * 16384 + (c0 + tx)];
  }
  __syncthreads();
#pragma unroll
  for(int i = 0; i < 4; ++i){
    int pix = c0 + ty * 4 + i;
    u32 pp = ((u32)(pix >> 7) + 1) * PROW + (pix & 127) + 1;
    op[(size_t)pp * 512 + (r0 + tx)] = f2bf(s[tx][ty * 4 + i]);
  }
}

// generic fp32 [rows][cols] -> bf16 [cols][rows] (used for xs -> XST)
__global__ __launch_bounds__(256) void k_transpose(const float* __restrict__ in,
                                                   u16* __restrict__ out,
                                                   int rows, int cols,
                                                   int ostride, size_t o_imgstride){
  __shared__ float s[32][33];
  const float* ip = in + (size_t)blockIdx.z * (size_t)rows * (size_t)cols;
  u16* op = out + (size_t)blockIdx.z * o_imgstride;
  int r0 = blockIdx.x * 32, c0 = blockIdx.y * 32;
  int tx = threadIdx.x, ty = threadIdx.y;
#pragma unroll
  for(int i = 0; i < 4; ++i){
    int r = ty * 4 + i;
    s[r][tx] = ip[(size_t)(r0 + r) * cols + (c0 + tx)];
  }
  __syncthreads();
#pragma unroll
  for(int i = 0; i < 4; ++i){
    int c = ty * 4 + i;
    op[(size_t)(c0 + c) * ostride + (r0 + tx)] = f2bf(s[tx][c]);
  }
}

// weights: [co][ci][3][3] f32 -> [e][co*co_mul+co_off][ci] bf16
__global__ __launch_bounds__(256) void k_wt(const float* __restrict__ in,
                                            u16* __restrict__ out,
                                            int co_mul, int co_off, int co_tot){
  int ci = blockIdx.x * 256 + threadIdx.x;   // 0..511
  int co = blockIdx.y;                       // 0..255
  int e  = blockIdx.z;                       // 0..8
  out[((size_t)e * co_tot + co * co_mul + co_off) * 512 + ci] =
      f2bf(in[((size_t)co * 512 + ci) * 9 + e]);
}

// ---------------------------------------------------------------------------
// scores8 MFMA: S8p[g][b][q=256][k=1280] partials, K-split over 8 tap-groups.
__global__ __launch_bounds__(256) void k_scores8(const u16* __restrict__ FUSEDP,
                                                 const u16* __restrict__ XST,
                                                 float* __restrict__ S8p){
  __shared__ u16 As[4096], Bs[4096];
  const int bz = blockIdx.z, b = bz >> 3, g = bz & 7;
  const int q0 = blockIdx.x * 128, k0 = blockIdx.y * 128;
  const int tid = threadIdx.x, w = tid >> 6, l = tid & 63;
  const int wr = w >> 1, wc = w & 1;
  const int l15 = l & 15, kg = (l >> 4) * 8;
  f32x4 acc[4][4];
#pragma unroll
  for(int m = 0; m < 4; ++m)
#pragma unroll
    for(int n = 0; n < 4; ++n) acc[m][n] = (f32x4){0.f, 0.f, 0.f, 0.f};

  for(int e8 = 0; e8 < 8; ++e8){
    const int e = g * 8 + e8, dy = e >> 3, dx = e & 7;
    for(int ci0 = 0; ci0 < 256; ci0 += 32){
#pragma unroll
      for(int r = 0; r < 2; ++r){
        const int idx = (w * 2 + r) * 64 + l;
        const int q = q0 + (idx >> 2);
        const int apy = ((q >> 4) << 3) + dy, apx = ((q & 15) << 3) + dx;
        const size_t pa = ((size_t)b * PIMG + (size_t)(apy + 1) * PROW + apx + 1) * 512
                          + ci0 + (idx & 3) * 8;
        gl16(FUSEDP + pa, As + (size_t)(w * 2 + r) * 512);
        const int k = k0 + (idx >> 2), t = k >> 8, rm = k & 255;
        const size_t pb = (((size_t)b * 5 + t) * 16384 +
                           (size_t)(((rm >> 4) << 3) + dy) * 128 + ((rm & 15) << 3) + dx) * 256
                          + ci0 + (idx & 3) * 8;
        gl16(XST + pb, Bs + (size_t)(w * 2 + r) * 512);
      }
      __syncthreads();
      bf16x8 af[4], bq[4];
#pragma unroll
      for(int m = 0; m < 4; ++m) af[m] = *(const bf16x8*)(As + (wr * 64 + m * 16 + l15) * 32 + kg);
#pragma unroll
      for(int n = 0; n < 4; ++n) bq[n] = *(const bf16x8*)(Bs + (wc * 64 + n * 16 + l15) * 32 + kg);
#pragma unroll
      for(int m = 0; m < 4; ++m)
#pragma unroll
        for(int n = 0; n < 4; ++n)
          acc[m][n] = __builtin_amdgcn_mfma_f32_16x16x32_bf16(af[m], bq[n], acc[m][n], 0, 0, 0);
      __syncthreads();
    }
  }
  float* dst = S8p + ((size_t)g * 2 + b) * 256 * 1280;
#pragma unroll
  for(int m = 0; m < 4; ++m){
    const int q = q0 + wr * 64 + m * 16 + (l >> 4) * 4;
#pragma unroll
    for(int n = 0; n < 4; ++n){
      const int k = k0 + wc * 64 + n * 16 + l15;
#pragma unroll
      for(int r = 0; r < 4; ++r) dst[(size_t)(q + r) * 1280 + k] = acc[m][n][r];
    }
  }
}

// softmax over k(1280), scale 1/128; sums 8 partials; writes A8 bf16.
__global__ __launch_bounds__(256) void k_softmax8(const float* __restrict__ S8p,
                                                  u16* __restrict__ A8){
  __shared__ float red[8];
  int b = blockIdx.x >> 8, q = blockIdx.x & 255;
  size_t roff = ((size_t)b * 256 + q) * 1280;
  int tid = threadIdx.x;
  float v[5]; float m = -1e30f;
#pragma unroll
  for(int i = 0; i < 5; ++i){
    size_t o = roff + tid + 256 * i;
    float s = 0.f;
#pragma unroll
    for(int g = 0; g < 8; ++g) s += S8p[(size_t)g * 655360 + o];
    v[i] = s * 0.0078125f; m = fmaxf(m, v[i]);
  }
#pragma unroll
  for(int o = 32; o > 0; o >>= 1) m = fmaxf(m, __shfl_xor(m, o));
  int wid = tid >> 6;
  if((tid & 63) == 0) red[wid] = m;
  __syncthreads();
  m = fmaxf(fmaxf(red[0], red[1]), fmaxf(red[2], red[3]));
  float s = 0.f;
#pragma unroll
  for(int i = 0; i < 5; ++i){ v[i] = __expf(v[i] - m); s += v[i]; }
#pragma unroll
  for(int o = 32; o > 0; o >>= 1) s += __shfl_xor(s, o);
  if((tid & 63) == 0) red[4 + wid] = s;
  __syncthreads();
  s = red[4] + red[5] + red[6] + red[7];
  float inv = 1.0f / s;
#pragma unroll
  for(int i = 0; i < 5; ++i) A8[roff + tid + 256 * i] = f2bf(v[i] * inv);
}

// scores16 from S8p quadrants, softmax over 320, scale 1/256 -> A16 bf16.
__global__ __launch_bounds__(320) void k_s16(const float* __restrict__ S8p,
                                             u16* __restrict__ A16){
  __shared__ float red[10];
  int b = blockIdx.x >> 6, q16 = blockIdx.x & 63;
  int tid = threadIdx.x;               // k16 in 0..319
  int t = tid >> 6, rm = tid & 63;
  int KY = rm >> 3, KX = rm & 7;
  int QY = q16 >> 3, QX = q16 & 7;
  float s = 0.f;
#pragma unroll
  for(int i = 0; i < 2; ++i)
#pragma unroll
    for(int j = 0; j < 2; ++j){
      int q8 = (2 * QY + i) * 16 + (2 * QX + j);
      int k8 = t * 256 + (2 * KY + i) * 16 + (2 * KX + j);
      size_t o = ((size_t)b * 256 + q8) * 1280 + k8;
#pragma unroll
      for(int g = 0; g < 8; ++g) s += S8p[(size_t)g * 655360 + o];
    }
  s *= 0.00390625f; // 1/256
  float m = s;
#pragma unroll
  for(int o = 32; o > 0; o >>= 1) m = fmaxf(m, __shfl_xor(m, o));
  int wid = tid >> 6;
  if((tid & 63) == 0) red[wid] = m;
  __syncthreads();
  m = fmaxf(fmaxf(fmaxf(red[0], red[1]), fmaxf(red[2], red[3])), red[4]);
  float e = __expf(s - m);
  float sm = e;
#pragma unroll
  for(int o = 32; o > 0; o >>= 1) sm += __shfl_xor(sm, o);
  if((tid & 63) == 0) red[5 + wid] = sm;
  __syncthreads();
  sm = red[5] + red[6] + red[7] + red[8] + red[9];
  A16[((size_t)b * 64 + q16) * 320 + tid] = f2bf(e / sm);
}

// ---------------------------------------------------------------------------
// val8 MFMA: per (b,ry,rx): OUT[q=256][ch=256] = A8[q][1280] @ Gt[ch][1280].
__global__ __launch_bounds__(256) void k_val8(const u16* __restrict__ A8,
                                              const u16* __restrict__ XST,
                                              u16* __restrict__ OUTCATP){
  __shared__ u16 As[4096];
  __shared__ u16 Bs[128 * 40];
  const int z = blockIdx.z, b = z >> 6, rr = z & 63;
  const int ry = rr >> 3, rx = rr & 7;
  const int q0 = blockIdx.x * 128, c0 = blockIdx.y * 128;
  const int tid = threadIdx.x, w = tid >> 6, l = tid & 63;
  const int wr = w >> 1, wc = w & 1;
  const int l15 = l & 15, kg = (l >> 4) * 8;
  const int k2 = tid >> 4, ch8 = tid & 15;   // B staging chunk
  f32x4 acc[4][4];
#pragma unroll
  for(int m = 0; m < 4; ++m)
#pragma unroll
    for(int n = 0; n < 4; ++n) acc[m][n] = (f32x4){0.f, 0.f, 0.f, 0.f};

  for(int k0 = 0; k0 < 1280; k0 += 32){
#pragma unroll
    for(int r = 0; r < 2; ++r){
      const int idx = (w * 2 + r) * 64 + l;
      const u16* ga = A8 + ((size_t)b * 256 + q0 + (idx >> 2)) * 1280 + k0 + (idx & 3) * 8;
      gl16(ga, As + (size_t)(w * 2 + r) * 512);
    }
    {
      const int ka = k0 + k2 * 2, kb = ka + 1;
      const int ta = ka >> 8, ra = ka & 255;
      const int tb = kb >> 8, rb = kb & 255;
      const size_t pa = (((size_t)b * 5 + ta) * 16384 +
                         (size_t)(((ra >> 4) << 3) + ry) * 128 + ((ra & 15) << 3) + rx) * 256
                        + c0 + ch8 * 8;
      const size_t pb = (((size_t)b * 5 + tb) * 16384 +
                         (size_t)(((rb >> 4) << 3) + ry) * 128 + ((rb & 15) << 3) + rx) * 256
                        + c0 + ch8 * 8;
      union { uint4 v; u16 s[8]; } u0, u1;
      u0.v = *(const uint4*)(XST + pa);
      u1.v = *(const uint4*)(XST + pb);
      const int kloc = k2 * 2, swz = (ch8 & 3) << 3;
#pragma unroll
      for(int j = 0; j < 8; ++j){
        u32 pack = (u32)u0.s[j] | ((u32)u1.s[j] << 16);
        *(u32*)(Bs + (size_t)(ch8 * 8 + j) * 40 + (kloc ^ swz)) = pack;
      }
    }
    __syncthreads();
    bf16x8 af[4], bq[4];
#pragma unroll
    for(int m = 0; m < 4; ++m) af[m] = *(const bf16x8*)(As + (wr * 64 + m * 16 + l15) * 32 + kg);
#pragma unroll
    for(int n = 0; n < 4; ++n){
      const int ch = wc * 64 + n * 16 + l15;
      bq[n] = *(const bf16x8*)(Bs + (size_t)ch * 40 + (kg ^ (((ch >> 3) & 3) << 3)));
    }
#pragma unroll
    for(int m = 0; m < 4; ++m)
#pragma unroll
      for(int n = 0; n < 4; ++n)
        acc[m][n] = __builtin_amdgcn_mfma_f32_16x16x32_bf16(af[m], bq[n], acc[m][n], 0, 0, 0);
    __syncthreads();
  }
#pragma unroll
  for(int m = 0; m < 4; ++m){
    const int qb = q0 + wr * 64 + m * 16 + (l >> 4) * 4;
#pragma unroll
    for(int n = 0; n < 4; ++n){
      const int ch = c0 + wc * 64 + n * 16 + l15;
#pragma unroll
      for(int r = 0; r < 4; ++r){
        const int q = qb + r;
        const int py = ((q >> 4) << 3) + ry, px = ((q & 15) << 3) + rx;
        OUTCATP[((size_t)b * PIMG + (size_t)(py + 1) * PROW + px + 1) * 512 + ch] = f2bf(acc[m][n][r]);
      }
    }
  }
}

// val16 MFMA (val8-clone, M=64, K=320): OUT[q=64][ch=128per-block] per
// (b,ry16,rx16) -> OUTCATP ch 256..511. A16 bf16 [b][64][320].
__global__ __launch_bounds__(256) void k_val16(const u16* __restrict__ A16,
                                               const u16* __restrict__ XST,
                                               u16* __restrict__ OUTCATP){
  __shared__ u16 As[64 * 32];
  __shared__ u16 Bs[128 * 40];
  const int z = blockIdx.z, b = z >> 8, rr = z & 255;
  const int ry = rr >> 4, rx = rr & 15;
  const int c0 = blockIdx.y * 128;
  const int tid = threadIdx.x, w = tid >> 6, l = tid & 63;
  const int l15 = l & 15, kg = (l >> 4) * 8;
  const int k2 = tid >> 4, ch8 = tid & 15;
  f32x4 acc[4][2];
#pragma unroll
  for(int m = 0; m < 4; ++m)
#pragma unroll
    for(int n = 0; n < 2; ++n) acc[m][n] = (f32x4){0.f, 0.f, 0.f, 0.f};

  for(int k0 = 0; k0 < 320; k0 += 32){
    {
      const int idx = w * 64 + l;
      const u16* ga = A16 + ((size_t)b * 64 + (idx >> 2)) * 320 + k0 + (idx & 3) * 8;
      gl16(ga, As + (size_t)w * 512);
    }
    {
      const int ka = k0 + k2 * 2, kb = ka + 1;
      const int ta = ka >> 6, ra = ka & 63;
      const int tb = kb >> 6, rb = kb & 63;
      const size_t pa = (((size_t)b * 5 + ta) * 16384 +
                         (size_t)(((ra >> 3) << 4) + ry) * 128 + ((ra & 7) << 4) + rx) * 256
                        + c0 + ch8 * 8;
      const size_t pb = (((size_t)b * 5 + tb) * 16384 +
                         (size_t)(((rb >> 3) << 4) + ry) * 128 + ((rb & 7) << 4) + rx) * 256
                        + c0 + ch8 * 8;
      union { uint4 v; u16 s[8]; } u0, u1;
      u0.v = *(const uint4*)(XST + pa);
      u1.v = *(const uint4*)(XST + pb);
      const int kloc = k2 * 2, swz = (ch8 & 3) << 3;
#pragma unroll
      for(int j = 0; j < 8; ++j){
        u32 pack = (u32)u0.s[j] | ((u32)u1.s[j] << 16);
        *(u32*)(Bs + (size_t)(ch8 * 8 + j) * 40 + (kloc ^ swz)) = pack;
      }
    }
    __syncthreads();
    bf16x8 af[4], bq[2];
#pragma unroll
    for(int m = 0; m < 4; ++m) af[m] = *(const bf16x8*)(As + (m * 16 + l15) * 32 + kg);
#pragma unroll
    for(int n = 0; n < 2; ++n){
      const int ch = w * 32 + n * 16 + l15;
      bq[n] = *(const bf16x8*)(Bs + (size_t)ch * 40 + (kg ^ (((ch >> 3) & 3) << 3)));
    }
#pragma unroll
    for(int m = 0; m < 4; ++m)
#pragma unroll
      for(int n = 0; n < 2; ++n)
        acc[m][n] = __builtin_amdgcn_mfma_f32_16x16x32_bf16(af[m], bq[n], acc[m][n], 0, 0, 0);
    __syncthreads();
  }
#pragma unroll
  for(int m = 0; m < 4; ++m){
    const int qb = m * 16 + (l >> 4) * 4;
#pragma unroll
    for(int n = 0; n < 2; ++n){
      const int ch = c0 + w * 32 + n * 16 + l15;
#pragma unroll
      for(int r = 0; r < 4; ++r){
        const int q = qb + r;
        const int py = ((q >> 3) << 4) + ry, px = ((q & 7) << 4) + rx;
        OUTCATP[((size_t)b * PIMG + (size_t)(py + 1) * PROW + px + 1) * 512 + 256 + ch] = f2bf(acc[m][n][r]);
      }
    }
  }
}

// ---------------------------------------------------------------------------
// conv<0> (lin): 128x128 tile, 2 blocks/CU, 2-barrier loop + counted vmcnt(4).
// ci-major K-order; padded A; per-lane const addressing. (R9-verified)
__global__ __launch_bounds__(512, 4) void k_convA(const u16* __restrict__ A,
                                                  const u16* __restrict__ W,
                                                  const float* __restrict__ bias,
                                                  u16* __restrict__ FUSEDP){
  constexpr int NT = 72;
  __shared__ u16 lds[2][16384];
  const int id = blockIdx.x;                     // 512 blocks
  const int wg = (id & 7) * 64 + (id >> 3);      // XCD-contiguous (512 = 8*64)
  const int mt = wg & 127, rest = wg >> 7;
  const int n0 = (rest & 1) * 128, b = rest >> 1;
  const int m0 = mt * 128;
  const int tid = threadIdx.x, w = tid >> 6, l = tid & 63;
  const int wr = w >> 2, wc = w & 3;
  const int l15 = l & 15, lq = l >> 4;
  const int lr = l >> 3;
  const u32 laneswz = (u32)((((l & 7) * 16) ^ (lr << 4)) >> 1);

  u32 aB[2], bB[2];
#pragma unroll
  for(int j = 0; j < 2; ++j){
    const int row = (w * 2 + j) * 8 + lr;
    const int p = m0 + row;
    aB[j] = ((u32)b * PIMG + ((u32)(p >> 7) + 1) * PROW + (u32)(p & 127) + 1) * 512 + laneswz;
    bB[j] = (u32)(n0 + row) * 512 + laneswz;
  }

  f32x4 acc[4][2];
#pragma unroll
  for(int m = 0; m < 4; ++m)
#pragma unroll
    for(int n = 0; n < 2; ++n) acc[m][n] = (f32x4){0.f, 0.f, 0.f, 0.f};

  auto STAGE = [&](int kt){
    const int e = kt % 9, ci0 = (kt / 9) << 6;   // ci-major
    const int dy = e / 3 - 1, dx = e % 3 - 1;
    const int aD = (dy * PROW + dx) * 512 + ci0;
    const u32 bD = (u32)e * 256u * 512u + ci0;
    u16* bufA = &lds[kt & 1][0];
    u16* bufB = &lds[kt & 1][8192];
#pragma unroll
    for(int j = 0; j < 2; ++j){
      const int c = w * 2 + j;
      gl16(A + aB[j] + aD, bufA + c * 512);
      gl16(W + bB[j] + bD, bufB + c * 512);
    }
  };

  STAGE(0);
  STAGE(1);

  for(int t = 0; t < NT; ++t){
    if(t < NT - 1) asm volatile("s_waitcnt vmcnt(4)" ::: "memory");
    else           asm volatile("s_waitcnt vmcnt(0)" ::: "memory");
    __builtin_amdgcn_s_barrier();
    const char* bufA = (const char*)&lds[t & 1][0];
    const char* bufB = bufA + 16384;
    bf16x8 af[4][2], bq[2][2];
#pragma unroll
    for(int m = 0; m < 4; ++m){
      const int row = wr * 64 + m * 16 + l15;
      const int sz = (row & 7) << 4;
#pragma unroll
      for(int kk = 0; kk < 2; ++kk)
        af[m][kk] = *(const bf16x8*)(bufA + row * 128 + (((kk * 4 + lq) * 16) ^ sz));
    }
#pragma unroll
    for(int n = 0; n < 2; ++n){
      const int row = wc * 32 + n * 16 + l15;
      const int sz = (row & 7) << 4;
#pragma unroll
      for(int kk = 0; kk < 2; ++kk)
        bq[n][kk] = *(const bf16x8*)(bufB + row * 128 + (((kk * 4 + lq) * 16) ^ sz));
    }
    asm volatile("s_waitcnt lgkmcnt(0)" ::: "memory");
    __builtin_amdgcn_sched_barrier(0);
    __builtin_amdgcn_s_barrier();
    if(t + 2 < NT) STAGE(t + 2);
    __builtin_amdgcn_s_setprio(1);
#pragma unroll
    for(int kk = 0; kk < 2; ++kk)
#pragma unroll
      for(int m = 0; m < 4; ++m)
#pragma unroll
        for(int n = 0; n < 2; ++n)
          MFMA16(acc[m][n], af[m][kk], bq[n][kk]);
    __builtin_amdgcn_s_setprio(0);
  }

#pragma unroll
  for(int m = 0; m < 4; ++m){
    const int p0 = m0 + wr * 64 + m * 16 + lq * 4;
    const size_t pp = ((size_t)b * PIMG + (size_t)((p0 >> 7) + 1) * PROW + (p0 & 127) + 1) * 512;
#pragma unroll
    for(int n = 0; n < 2; ++n){
      const int co = n0 + wc * 32 + n * 16 + l15;
      const float bi = bias[co];
#pragma unroll
      for(int r = 0; r < 4; ++r){
        float v = acc[m][n][r] + bi;
        v = v > 0.f ? v : 0.2f * v;
        FUSEDP[pp + (size_t)r * 512 + 256 + co] = f2bf(v);
      }
    }
  }
}

// ---------------------------------------------------------------------------
// conv<1> (gate/feat fused): 16-wave block, BM=BN=256, BK=64 (128B rows,
// 0-conflict swizzle), 4 waves/SIMD, 2-barrier loop + counted vmcnt(4),
// ci-major K-order; per-kk fragment reload keeps VGPR < 128.
__global__ __launch_bounds__(1024, 4) void k_convB16(const u16* __restrict__ A,
                                                     const u16* __restrict__ W,
                                                     const float* __restrict__ bias,
                                                     const float* __restrict__ bias2,
                                                     float* __restrict__ out){
  constexpr int NT = 72;
  __shared__ u16 lds[2][32768];                  // A [256][64] @0, B @16384 (u16)
  const int id = blockIdx.x;                     // 256 blocks
  const int wg = (id & 7) * 32 + (id >> 3);      // XCD-contiguous (256 = 8*32)
  const int ntile = wg >> 7;
  const int rem = wg & 127, b = rem >> 6, mt = rem & 63;
  const int m0 = mt * 256, n0 = ntile * 256;
  const int tid = threadIdx.x, w = tid >> 6, l = tid & 63;
  const int wr = w >> 2, wc = w & 3;             // 4 x 4 waves -> per-wave 64x64
  const int l15 = l & 15, lq = l >> 4;
  const int lr = l >> 3;
  const u32 laneswz = (u32)((((l & 7) * 16) ^ (lr << 4)) >> 1);

  u32 aB[2], bB[2];
#pragma unroll
  for(int j = 0; j < 2; ++j){
    const int row = (w * 2 + j) * 8 + lr;        // 32 chunks of 8 rows
    const int p = m0 + row;
    aB[j] = ((u32)b * PIMG + ((u32)(p >> 7) + 1) * PROW + (u32)(p & 127) + 1) * 512 + laneswz;
    bB[j] = (u32)(n0 + row) * 512 + laneswz;
  }

  f32x4 acc[4][4];
#pragma unroll
  for(int m = 0; m < 4; ++m)
#pragma unroll
    for(int n = 0; n < 4; ++n) acc[m][n] = (f32x4){0.f, 0.f, 0.f, 0.f};

  auto STAGE = [&](int kt){
    const int e = kt % 9, ci0 = (kt / 9) << 6;   // ci-major
    const int dy = e / 3 - 1, dx = e % 3 - 1;
    const int aD = (dy * PROW + dx) * 512 + ci0;
    const u32 bD = (u32)e * 512u * 512u + ci0;
    u16* bufA = &lds[kt & 1][0];
    u16* bufB = &lds[kt & 1][16384];
#pragma unroll
    for(int j = 0; j < 2; ++j){
      const int c = w * 2 + j;
      gl16(A + aB[j] + aD, bufA + c * 512);
      gl16(W + bB[j] + bD, bufB + c * 512);
    }
  };

  STAGE(0);
  STAGE(1);

  for(int t = 0; t < NT; ++t){
    if(t < NT - 1) asm volatile("s_waitcnt vmcnt(4)" ::: "memory");
    else           asm volatile("s_waitcnt vmcnt(0)" ::: "memory");
    __builtin_amdgcn_s_barrier();                  // buf[t&1] data visible
    const char* bufA = (const char*)&lds[t & 1][0];
    const char* bufB = bufA + 32768;
    bf16x8 af[4], bq[4];
    // ---- kk = 0: read 8 frags, drain, MFMA 16 (overlaps kk=1 read issue)
#pragma unroll
    for(int m = 0; m < 4; ++m){
      const int row = wr * 64 + m * 16 + l15;
      af[m] = *(const bf16x8*)(bufA + row * 128 + ((lq * 16) ^ ((row & 7) << 4)));
    }
#pragma unroll
    for(int n = 0; n < 4; ++n){
      const int row = wc * 64 + n * 16 + l15;
      bq[n] = *(const bf16x8*)(bufB + row * 128 + ((lq * 16) ^ ((row & 7) << 4)));
    }
    asm volatile("s_waitcnt lgkmcnt(0)" ::: "memory");
    __builtin_amdgcn_sched_barrier(0);
    __builtin_amdgcn_s_setprio(1);
#pragma unroll
    for(int m = 0; m < 4; ++m)
#pragma unroll
      for(int n = 0; n < 4; ++n)
        MFMA16(acc[m][n], af[m], bq[n]);
    __builtin_amdgcn_s_setprio(0);
    // ---- kk = 1: reuse frag registers
#pragma unroll
    for(int m = 0; m < 4; ++m){
      const int row = wr * 64 + m * 16 + l15;
      af[m] = *(const bf16x8*)(bufA + row * 128 + ((64 + lq * 16) ^ ((row & 7) << 4)));
    }
#pragma unroll
    for(int n = 0; n < 4; ++n){
      const int row = wc * 64 + n * 16 + l15;
      bq[n] = *(const bf16x8*)(bufB + row * 128 + ((64 + lq * 16) ^ ((row & 7) << 4)));
    }
    asm volatile("s_waitcnt lgkmcnt(0)" ::: "memory");
    __builtin_amdgcn_sched_barrier(0);
    __builtin_amdgcn_s_barrier();                  // all reads of buf[t&1] done
    if(t + 2 < NT) STAGE(t + 2);                   // refill just-freed buffer
    __builtin_amdgcn_s_setprio(1);
#pragma unroll
    for(int m = 0; m < 4; ++m)
#pragma unroll
      for(int n = 0; n < 4; ++n)
        MFMA16(acc[m][n], af[m], bq[n]);
    __builtin_amdgcn_s_setprio(0);
  }

#pragma unroll
  for(int m = 0; m < 4; ++m){
    const int p0 = m0 + wr * 64 + m * 16 + lq * 4;
#pragma unroll
    for(int n = 0; n < 4; ++n){
      const int col = n0 + wc * 64 + n * 16 + l15;
      const int s = col & 1, co = col >> 1;
      const float big = bias[co], bif = bias2[co];
      float res[4];
#pragma unroll
      for(int r = 0; r < 4; ++r){
        const float val = acc[m][n][r];
        const float oth = __shfl_xor(val, 1);
        float gg = s ? oth : val;
        float ff = s ? val : oth;
        gg += big; ff += bif;
        ff = ff > 0.f ? ff : 0.2f * ff;
        res[r] = ff / (1.0f + __expf(-gg));
      }
      if(s == 0){
        float4 v4 = make_float4(res[0], res[1], res[2], res[3]);
        *(float4*)&out[((size_t)b * 256 + co) * 16384 + p0] = v4;
      }
    }
  }
}

// ---------------------------------------------------------------------------
extern "C" void kernel_launch(void* const* d_in, const int* in_sizes, int n_in,
                              void* d_out, int out_size, void* d_ws, size_t ws_size,
                              hipStream_t stream){
  const float* x      = (const float*)d_in[0];
  const float* xs     = (const float*)d_in[1];
  // d_in[2] = ms : unused (mask is a no-op in the reference)
  const float* w_lin  = (const float*)d_in[3];
  const float* b_lin  = (const float*)d_in[4];
  const float* w_gate = (const float*)d_in[5];
  const float* b_gate = (const float*)d_in[6];
  const float* w_feat = (const float*)d_in[7];
  const float* b_feat = (const float*)d_in[8];
  float* out = (float*)d_out;

  char* ws = (char*)d_ws;
  size_t off = 0;
  auto alloc = [&](size_t bytes) -> void* {
    void* p = ws + off;
    off += (bytes + 255) & ~(size_t)255;
    return p;
  };
  u16* FUSEDP  = (u16*)alloc(2ull * PIMGC * 2);       // padded [b][130][130][512]
  u16* OUTCATP = (u16*)alloc(2ull * PIMGC * 2);       // padded [b][130][130][512]
  u16* XST     = (u16*)alloc(10ull * 16384 * 256 * 2);// xs NHWC bf16
  u16* WTl     = (u16*)alloc(9ull * 256 * 512 * 2);   // [e][co][ci]
  u16* WGF     = (u16*)alloc(9ull * 512 * 512 * 2);   // [e][2co+s][ci]
  float* S8p   = (float*)alloc(8ull * 655360 * 4);    // [g][b][256][1280]
  u16* A8      = (u16*)alloc(655360ull * 2);          // bf16 [b][256][1280]
  u16* A16     = (u16*)alloc(2ull * 64 * 320 * 2);    // bf16 [b][64][320]

  // zero padded borders (interior written by producers)
  k_border<<<dim3(129, 2), 256, 0, stream>>>(FUSEDP);
  k_border<<<dim3(129, 2), 256, 0, stream>>>(OUTCATP);

  dim3 tb(32, 8);
  k_transpose_pad<<<dim3(8, 512, 2), tb, 0, stream>>>(x, FUSEDP);
  k_transpose<<<dim3(8, 512, 10), tb, 0, stream>>>(xs, XST, 256, 16384, 256, 4194304ull);

  k_wt<<<dim3(2, 256, 9), 256, 0, stream>>>(w_lin,  WTl, 1, 0, 256);
  k_wt<<<dim3(2, 256, 9), 256, 0, stream>>>(w_gate, WGF, 2, 0, 512);
  k_wt<<<dim3(2, 256, 9), 256, 0, stream>>>(w_feat, WGF, 2, 1, 512);

  k_scores8<<<dim3(2, 10, 16), 256, 0, stream>>>(FUSEDP, XST, S8p);
  k_softmax8<<<512, 256, 0, stream>>>(S8p, A8);
  k_s16<<<128, 320, 0, stream>>>(S8p, A16);

  k_val8 <<<dim3(2, 2, 128), 256, 0, stream>>>(A8, XST, OUTCATP);
  k_val16<<<dim3(1, 2, 512), 256, 0, stream>>>(A16, XST, OUTCATP);

  k_convA<<<512, 512, 0, stream>>>(OUTCATP, WTl, b_lin, FUSEDP);
  k_convB16<<<256, 1024, 0, stream>>>(FUSEDP, WGF, b_gate, b_feat, out);
}

// Round 12
// 391.721 us; speedup vs baseline: 1.1427x; 1.0344x over previous
//
#include <hip/hip_runtime.h>

typedef unsigned short u16;
typedef unsigned int u32;
typedef __attribute__((ext_vector_type(8))) short bf16x8;   // 8 bf16 = 4 VGPR
typedef __attribute__((ext_vector_type(4))) float f32x4;

#define MFMA16(d, a, bb) d = __builtin_amdgcn_mfma_f32_16x16x32_bf16(a, bb, d, 0, 0, 0)

// padded image geometry: [b][130][130][512], 1-px zero border
#define PROW 130
#define PIMG 16900              // 130*130 pixels
#define PIMGC (16900 * 512)     // u16 per image

__device__ __forceinline__ u16 f2bf(float f){
  union { float f; u32 i; } v; v.f = f;
  u32 r = v.i + 0x7fffu + ((v.i >> 16) & 1u);
  return (u16)(r >> 16);
}

// async global->LDS, 16B per lane; LDS dest = wave-uniform base + lane*16
__device__ __forceinline__ void gl16(const u16* g, u16* l){
  __builtin_amdgcn_global_load_lds(
      (const __attribute__((address_space(1))) u32*)g,
      (__attribute__((address_space(3))) u32*)l, 16, 0, 0);
}

// ---------------------------------------------------------------------------
// zero the 1-px border of a padded [2][130][130][512] buffer
__global__ __launch_bounds__(256) void k_border(u16* __restrict__ buf){
  const int b = blockIdx.y;
  const int j = blockIdx.x * 4 + (threadIdx.x >> 6);   // 0..515
  const int l = threadIdx.x & 63;
  int pp;
  if(j < 130)       pp = j;                      // top row
  else if(j < 260)  pp = 129 * 130 + (j - 130);  // bottom row
  else if(j < 388)  pp = (j - 259) * 130;        // left col rows 1..128
  else              pp = (j - 387) * 130 + 129;  // right col rows 1..128
  u16* p = buf + ((size_t)b * PIMG + pp) * 512 + l * 8;
  *(uint4*)p = (uint4){0u, 0u, 0u, 0u};
}

// x: fp32 [256][16384] -> FUSEDP padded [pix][ch] bf16, ch 0..255.
// 64ch x 32pix tiles; 128B-coalesced loads AND stores.
__global__ __launch_bounds__(256) void k_transPadW(const float* __restrict__ in,
                                                   u16* __restrict__ out){
  __shared__ float s[64][33];
  const float* ip = in + (size_t)blockIdx.z * 256 * 16384;
  u16* op = out + (size_t)blockIdx.z * PIMGC;
  const int r0 = blockIdx.x * 64, c0 = blockIdx.y * 32;
  const int tx = threadIdx.x, ty = threadIdx.y;
#pragma unroll
  for(int i = 0; i < 8; ++i){
    int r = ty * 8 + i;
    s[r][tx] = ip[(size_t)(r0 + r) * 16384 + (c0 + tx)];
  }
  __syncthreads();
  const int tid = ty * 32 + tx;
  const int p = tid >> 3, cs = (tid & 7) * 8;
  const int pix = c0 + p;
  const u32 pp = ((u32)(pix >> 7) + 1) * PROW + (pix & 127) + 1;
  union { uint4 v; u16 h[8]; } pk;
#pragma unroll
  for(int i = 0; i < 8; ++i) pk.h[i] = f2bf(s[cs + i][p]);
  *(uint4*)(op + (size_t)pp * 512 + r0 + cs) = pk.v;
}

// xs: fp32 [256][cols] -> bf16 [pix][ostride] per image; wide stores.
__global__ __launch_bounds__(256) void k_transW(const float* __restrict__ in,
                                                u16* __restrict__ out,
                                                int cols, int ostride,
                                                size_t o_imgstride){
  __shared__ float s[64][33];
  const float* ip = in + (size_t)blockIdx.z * 256 * (size_t)cols;
  u16* op = out + (size_t)blockIdx.z * o_imgstride;
  const int r0 = blockIdx.x * 64, c0 = blockIdx.y * 32;
  const int tx = threadIdx.x, ty = threadIdx.y;
#pragma unroll
  for(int i = 0; i < 8; ++i){
    int r = ty * 8 + i;
    s[r][tx] = ip[(size_t)(r0 + r) * cols + (c0 + tx)];
  }
  __syncthreads();
  const int tid = ty * 32 + tx;
  const int p = tid >> 3, cs = (tid & 7) * 8;
  union { uint4 v; u16 h[8]; } pk;
#pragma unroll
  for(int i = 0; i < 8; ++i) pk.h[i] = f2bf(s[cs + i][p]);
  *(uint4*)(op + (size_t)(c0 + p) * ostride + r0 + cs) = pk.v;
}

// weights: [co][ci][3][3] f32 -> [e][co*co_mul+co_off][ci] bf16.
// Per-thread contiguous 9-tap read; 128B-coalesced writes per tap.
__global__ __launch_bounds__(512) void k_wt2(const float* __restrict__ in,
                                             u16* __restrict__ out,
                                             int co_mul, int co_off, int co_tot){
  const int ci = threadIdx.x;   // 0..511
  const int co = blockIdx.x;    // 0..255
  const float* src = in + ((size_t)co * 512 + ci) * 9;
  float v[9];
#pragma unroll
  for(int e = 0; e < 9; ++e) v[e] = src[e];
#pragma unroll
  for(int e = 0; e < 9; ++e)
    out[((size_t)e * co_tot + co * co_mul + co_off) * 512 + ci] = f2bf(v[e]);
}

// ---------------------------------------------------------------------------
// scores8 MFMA v2 (convA-clone): S8p[g][b][q=256][k=1280] partials; per block
// dy = g (fixed), dx = e8 sweeps. BM=BN=128, BK=64, 8 waves, double-buffered
// counted vmcnt(4), 0-conflict swizzle, per-lane-const staging bases.
__global__ __launch_bounds__(512, 4) void k_scores8(const u16* __restrict__ FUSEDP,
                                                    const u16* __restrict__ XST,
                                                    float* __restrict__ S8p){
  constexpr int NT = 32;                         // 4 ci-blocks x 8 taps
  __shared__ u16 lds[2][16384];                  // A [128][64] @0, B @8192 (u16)
  const int bz = blockIdx.z, b = bz >> 3, g = bz & 7;
  const int q0 = blockIdx.x * 128, k0 = blockIdx.y * 128;
  const int tid = threadIdx.x, w = tid >> 6, l = tid & 63;
  const int wr = w >> 2, wc = w & 3;             // 2 x 4 waves -> per-wave 64x32
  const int l15 = l & 15, lq = l >> 4;
  const int lr = l >> 3, lc = l & 7;
  const u32 laneswz = (u32)(((lc * 16) ^ (lr << 4)) >> 1);

  u32 aB[2], bB[2];
#pragma unroll
  for(int j = 0; j < 2; ++j){
    const int row = (w * 2 + j) * 8 + lr;
    const int q = q0 + row, qy = q >> 4, qx = q & 15;
    const u32 pp = (u32)(qy * 8 + g + 1) * PROW + qx * 8 + 1;
    aB[j] = ((u32)b * PIMG + pp) * 512 + laneswz;
    const int k = k0 + row, t = k >> 8, rm = k & 255;
    const u32 bpix = (u32)((rm >> 4) * 8 + g) * 128 + (rm & 15) * 8;
    bB[j] = (((u32)b * 5 + t) * 16384 + bpix) * 256 + laneswz;
  }

  f32x4 acc[4][2];
#pragma unroll
  for(int m = 0; m < 4; ++m)
#pragma unroll
    for(int n = 0; n < 2; ++n) acc[m][n] = (f32x4){0.f, 0.f, 0.f, 0.f};

  auto STAGE = [&](int kt){
    const int e8 = kt & 7, ci0 = (kt >> 3) << 6;
    const int aD = e8 * 512 + ci0;               // dx shifts pixel by +1 (u16*512)
    const int bD = e8 * 256 + ci0;
    u16* bufA = &lds[kt & 1][0];
    u16* bufB = &lds[kt & 1][8192];
#pragma unroll
    for(int j = 0; j < 2; ++j){
      const int c = w * 2 + j;
      gl16(FUSEDP + aB[j] + aD, bufA + c * 512);
      gl16(XST + bB[j] + bD, bufB + c * 512);
    }
  };

  STAGE(0);
  STAGE(1);

  for(int t = 0; t < NT; ++t){
    if(t < NT - 1) asm volatile("s_waitcnt vmcnt(4)" ::: "memory");
    else           asm volatile("s_waitcnt vmcnt(0)" ::: "memory");
    __builtin_amdgcn_s_barrier();
    const char* bufA = (const char*)&lds[t & 1][0];
    const char* bufB = bufA + 16384;
    bf16x8 af[4][2], bq[2][2];
#pragma unroll
    for(int m = 0; m < 4; ++m){
      const int row = wr * 64 + m * 16 + l15;
      const int sz = (row & 7) << 4;
#pragma unroll
      for(int kk = 0; kk < 2; ++kk)
        af[m][kk] = *(const bf16x8*)(bufA + row * 128 + (((kk * 4 + lq) * 16) ^ sz));
    }
#pragma unroll
    for(int n = 0; n < 2; ++n){
      const int row = wc * 32 + n * 16 + l15;
      const int sz = (row & 7) << 4;
#pragma unroll
      for(int kk = 0; kk < 2; ++kk)
        bq[n][kk] = *(const bf16x8*)(bufB + row * 128 + (((kk * 4 + lq) * 16) ^ sz));
    }
    asm volatile("s_waitcnt lgkmcnt(0)" ::: "memory");
    __builtin_amdgcn_sched_barrier(0);
    __builtin_amdgcn_s_barrier();
    if(t + 2 < NT) STAGE(t + 2);
    __builtin_amdgcn_s_setprio(1);
#pragma unroll
    for(int kk = 0; kk < 2; ++kk)
#pragma unroll
      for(int m = 0; m < 4; ++m)
#pragma unroll
        for(int n = 0; n < 2; ++n)
          MFMA16(acc[m][n], af[m][kk], bq[n][kk]);
    __builtin_amdgcn_s_setprio(0);
  }

  float* dst = S8p + ((size_t)g * 2 + b) * 256 * 1280;
#pragma unroll
  for(int m = 0; m < 4; ++m){
    const int q = q0 + wr * 64 + m * 16 + lq * 4;
#pragma unroll
    for(int n = 0; n < 2; ++n){
      const int k = k0 + wc * 32 + n * 16 + l15;
#pragma unroll
      for(int r = 0; r < 4; ++r) dst[(size_t)(q + r) * 1280 + k] = acc[m][n][r];
    }
  }
}

// softmax over k(1280), scale 1/128; sums 8 partials; writes A8 bf16.
__global__ __launch_bounds__(256) void k_softmax8(const float* __restrict__ S8p,
                                                  u16* __restrict__ A8){
  __shared__ float red[8];
  int b = blockIdx.x >> 8, q = blockIdx.x & 255;
  size_t roff = ((size_t)b * 256 + q) * 1280;
  int tid = threadIdx.x;
  float v[5]; float m = -1e30f;
#pragma unroll
  for(int i = 0; i < 5; ++i){
    size_t o = roff + tid + 256 * i;
    float s = 0.f;
#pragma unroll
    for(int g = 0; g < 8; ++g) s += S8p[(size_t)g * 655360 + o];
    v[i] = s * 0.0078125f; m = fmaxf(m, v[i]);
  }
#pragma unroll
  for(int o = 32; o > 0; o >>= 1) m = fmaxf(m, __shfl_xor(m, o));
  int wid = tid >> 6;
  if((tid & 63) == 0) red[wid] = m;
  __syncthreads();
  m = fmaxf(fmaxf(red[0], red[1]), fmaxf(red[2], red[3]));
  float s = 0.f;
#pragma unroll
  for(int i = 0; i < 5; ++i){ v[i] = __expf(v[i] - m); s += v[i]; }
#pragma unroll
  for(int o = 32; o > 0; o >>= 1) s += __shfl_xor(s, o);
  if((tid & 63) == 0) red[4 + wid] = s;
  __syncthreads();
  s = red[4] + red[5] + red[6] + red[7];
  float inv = 1.0f / s;
#pragma unroll
  for(int i = 0; i < 5; ++i) A8[roff + tid + 256 * i] = f2bf(v[i] * inv);
}

// scores16 from S8p quadrants, softmax over 320, scale 1/256 -> A16 bf16.
__global__ __launch_bounds__(320) void k_s16(const float* __restrict__ S8p,
                                             u16* __restrict__ A16){
  __shared__ float red[10];
  int b = blockIdx.x >> 6, q16 = blockIdx.x & 63;
  int tid = threadIdx.x;               // k16 in 0..319
  int t = tid >> 6, rm = tid & 63;
  int KY = rm >> 3, KX = rm & 7;
  int QY = q16 >> 3, QX = q16 & 7;
  float s = 0.f;
#pragma unroll
  for(int i = 0; i < 2; ++i)
#pragma unroll
    for(int j = 0; j < 2; ++j){
      int q8 = (2 * QY + i) * 16 + (2 * QX + j);
      int k8 = t * 256 + (2 * KY + i) * 16 + (2 * KX + j);
      size_t o = ((size_t)b * 256 + q8) * 1280 + k8;
#pragma unroll
      for(int g = 0; g < 8; ++g) s += S8p[(size_t)g * 655360 + o];
    }
  s *= 0.00390625f; // 1/256
  float m = s;
#pragma unroll
  for(int o = 32; o > 0; o >>= 1) m = fmaxf(m, __shfl_xor(m, o));
  int wid = tid >> 6;
  if((tid & 63) == 0) red[wid] = m;
  __syncthreads();
  m = fmaxf(fmaxf(fmaxf(red[0], red[1]), fmaxf(red[2], red[3])), red[4]);
  float e = __expf(s - m);
  float sm = e;
#pragma unroll
  for(int o = 32; o > 0; o >>= 1) sm += __shfl_xor(sm, o);
  if((tid & 63) == 0) red[5 + wid] = sm;
  __syncthreads();
  sm = red[5] + red[6] + red[7] + red[8] + red[9];
  A16[((size_t)b * 64 + q16) * 320 + tid] = f2bf(e / sm);
}

// ---------------------------------------------------------------------------
// val8 MFMA: per (b,ry,rx): OUT[q=256][ch=256] = A8[q][1280] @ Gt[ch][1280].
__global__ __launch_bounds__(256) void k_val8(const u16* __restrict__ A8,
                                              const u16* __restrict__ XST,
                                              u16* __restrict__ OUTCATP){
  __shared__ u16 As[4096];
  __shared__ u16 Bs[128 * 40];
  const int z = blockIdx.z, b = z >> 6, rr = z & 63;
  const int ry = rr >> 3, rx = rr & 7;
  const int q0 = blockIdx.x * 128, c0 = blockIdx.y * 128;
  const int tid = threadIdx.x, w = tid >> 6, l = tid & 63;
  const int wr = w >> 1, wc = w & 1;
  const int l15 = l & 15, kg = (l >> 4) * 8;
  const int k2 = tid >> 4, ch8 = tid & 15;   // B staging chunk
  f32x4 acc[4][4];
#pragma unroll
  for(int m = 0; m < 4; ++m)
#pragma unroll
    for(int n = 0; n < 4; ++n) acc[m][n] = (f32x4){0.f, 0.f, 0.f, 0.f};

  for(int k0 = 0; k0 < 1280; k0 += 32){
#pragma unroll
    for(int r = 0; r < 2; ++r){
      const int idx = (w * 2 + r) * 64 + l;
      const u16* ga = A8 + ((size_t)b * 256 + q0 + (idx >> 2)) * 1280 + k0 + (idx & 3) * 8;
      gl16(ga, As + (size_t)(w * 2 + r) * 512);
    }
    {
      const int ka = k0 + k2 * 2, kb = ka + 1;
      const int ta = ka >> 8, ra = ka & 255;
      const int tb = kb >> 8, rb = kb & 255;
      const size_t pa = (((size_t)b * 5 + ta) * 16384 +
                         (size_t)(((ra >> 4) << 3) + ry) * 128 + ((ra & 15) << 3) + rx) * 256
                        + c0 + ch8 * 8;
      const size_t pb = (((size_t)b * 5 + tb) * 16384 +
                         (size_t)(((rb >> 4) << 3) + ry) * 128 + ((rb & 15) << 3) + rx) * 256
                        + c0 + ch8 * 8;
      union { uint4 v; u16 s[8]; } u0, u1;
      u0.v = *(const uint4*)(XST + pa);
      u1.v = *(const uint4*)(XST + pb);
      const int kloc = k2 * 2, swz = (ch8 & 3) << 3;
#pragma unroll
      for(int j = 0; j < 8; ++j){
        u32 pack = (u32)u0.s[j] | ((u32)u1.s[j] << 16);
        *(u32*)(Bs + (size_t)(ch8 * 8 + j) * 40 + (kloc ^ swz)) = pack;
      }
    }
    __syncthreads();
    bf16x8 af[4], bq[4];
#pragma unroll
    for(int m = 0; m < 4; ++m) af[m] = *(const bf16x8*)(As + (wr * 64 + m * 16 + l15) * 32 + kg);
#pragma unroll
    for(int n = 0; n < 4; ++n){
      const int ch = wc * 64 + n * 16 + l15;
      bq[n] = *(const bf16x8*)(Bs + (size_t)ch * 40 + (kg ^ (((ch >> 3) & 3) << 3)));
    }
#pragma unroll
    for(int m = 0; m < 4; ++m)
#pragma unroll
      for(int n = 0; n < 4; ++n)
        acc[m][n] = __builtin_amdgcn_mfma_f32_16x16x32_bf16(af[m], bq[n], acc[m][n], 0, 0, 0);
    __syncthreads();
  }
#pragma unroll
  for(int m = 0; m < 4; ++m){
    const int qb = q0 + wr * 64 + m * 16 + (l >> 4) * 4;
#pragma unroll
    for(int n = 0; n < 4; ++n){
      const int ch = c0 + wc * 64 + n * 16 + l15;
#pragma unroll
      for(int r = 0; r < 4; ++r){
        const int q = qb + r;
        const int py = ((q >> 4) << 3) + ry, px = ((q & 15) << 3) + rx;
        OUTCATP[((size_t)b * PIMG + (size_t)(py + 1) * PROW + px + 1) * 512 + ch] = f2bf(acc[m][n][r]);
      }
    }
  }
}

// val16 MFMA (val8-clone, M=64, K=320): OUT[q=64][ch=128per-block] per
// (b,ry16,rx16) -> OUTCATP ch 256..511. A16 bf16 [b][64][320].
__global__ __launch_bounds__(256) void k_val16(const u16* __restrict__ A16,
                                               const u16* __restrict__ XST,
                                               u16* __restrict__ OUTCATP){
  __shared__ u16 As[64 * 32];
  __shared__ u16 Bs[128 * 40];
  const int z = blockIdx.z, b = z >> 8, rr = z & 255;
  const int ry = rr >> 4, rx = rr & 15;
  const int c0 = blockIdx.y * 128;
  const int tid = threadIdx.x, w = tid >> 6, l = tid & 63;
  const int l15 = l & 15, kg = (l >> 4) * 8;
  const int k2 = tid >> 4, ch8 = tid & 15;
  f32x4 acc[4][2];
#pragma unroll
  for(int m = 0; m < 4; ++m)
#pragma unroll
    for(int n = 0; n < 2; ++n) acc[m][n] = (f32x4){0.f, 0.f, 0.f, 0.f};

  for(int k0 = 0; k0 < 320; k0 += 32){
    {
      const int idx = w * 64 + l;
      const u16* ga = A16 + ((size_t)b * 64 + (idx >> 2)) * 320 + k0 + (idx & 3) * 8;
      gl16(ga, As + (size_t)w * 512);
    }
    {
      const int ka = k0 + k2 * 2, kb = ka + 1;
      const int ta = ka >> 6, ra = ka & 63;
      const int tb = kb >> 6, rb = kb & 63;
      const size_t pa = (((size_t)b * 5 + ta) * 16384 +
                         (size_t)(((ra >> 3) << 4) + ry) * 128 + ((ra & 7) << 4) + rx) * 256
                        + c0 + ch8 * 8;
      const size_t pb = (((size_t)b * 5 + tb) * 16384 +
                         (size_t)(((rb >> 3) << 4) + ry) * 128 + ((rb & 7) << 4) + rx) * 256
                        + c0 + ch8 * 8;
      union { uint4 v; u16 s[8]; } u0, u1;
      u0.v = *(const uint4*)(XST + pa);
      u1.v = *(const uint4*)(XST + pb);
      const int kloc = k2 * 2, swz = (ch8 & 3) << 3;
#pragma unroll
      for(int j = 0; j < 8; ++j){
        u32 pack = (u32)u0.s[j] | ((u32)u1.s[j] << 16);
        *(u32*)(Bs + (size_t)(ch8 * 8 + j) * 40 + (kloc ^ swz)) = pack;
      }
    }
    __syncthreads();
    bf16x8 af[4], bq[2];
#pragma unroll
    for(int m = 0; m < 4; ++m) af[m] = *(const bf16x8*)(As + (m * 16 + l15) * 32 + kg);
#pragma unroll
    for(int n = 0; n < 2; ++n){
      const int ch = w * 32 + n * 16 + l15;
      bq[n] = *(const bf16x8*)(Bs + (size_t)ch * 40 + (kg ^ (((ch >> 3) & 3) << 3)));
    }
#pragma unroll
    for(int m = 0; m < 4; ++m)
#pragma unroll
      for(int n = 0; n < 2; ++n)
        acc[m][n] = __builtin_amdgcn_mfma_f32_16x16x32_bf16(af[m], bq[n], acc[m][n], 0, 0, 0);
    __syncthreads();
  }
#pragma unroll
  for(int m = 0; m < 4; ++m){
    const int qb = m * 16 + (l >> 4) * 4;
#pragma unroll
    for(int n = 0; n < 2; ++n){
      const int ch = c0 + w * 32 + n * 16 + l15;
#pragma unroll
      for(int r = 0; r < 4; ++r){
        const int q = qb + r;
        const int py = ((q >> 3) << 4) + ry, px = ((q & 7) << 4) + rx;
        OUTCATP[((size_t)b * PIMG + (size_t)(py + 1) * PROW + px + 1) * 512 + 256 + ch] = f2bf(acc[m][n][r]);
      }
    }
  }
}

// ---------------------------------------------------------------------------
// conv<0> (lin): 128x128 tile, 2 blocks/CU, 2-barrier loop + counted vmcnt(4).
// ci-major K-order; padded A; per-lane const addressing. (R9-verified)
__global__ __launch_bounds__(512, 4) void k_convA(const u16* __restrict__ A,
                                                  const u16* __restrict__ W,
                                                  const float* __restrict__ bias,
                                                  u16* __restrict__ FUSEDP){
  constexpr int NT = 72;
  __shared__ u16 lds[2][16384];
  const int id = blockIdx.x;                     // 512 blocks
  const int wg = (id & 7) * 64 + (id >> 3);      // XCD-contiguous (512 = 8*64)
  const int mt = wg & 127, rest = wg >> 7;
  const int n0 = (rest & 1) * 128, b = rest >> 1;
  const int m0 = mt * 128;
  const int tid = threadIdx.x, w = tid >> 6, l = tid & 63;
  const int wr = w >> 2, wc = w & 3;
  const int l15 = l & 15, lq = l >> 4;
  const int lr = l >> 3;
  const u32 laneswz = (u32)((((l & 7) * 16) ^ (lr << 4)) >> 1);

  u32 aB[2], bB[2];
#pragma unroll
  for(int j = 0; j < 2; ++j){
    const int row = (w * 2 + j) * 8 + lr;
    const int p = m0 + row;
    aB[j] = ((u32)b * PIMG + ((u32)(p >> 7) + 1) * PROW + (u32)(p & 127) + 1) * 512 + laneswz;
    bB[j] = (u32)(n0 + row) * 512 + laneswz;
  }

  f32x4 acc[4][2];
#pragma unroll
  for(int m = 0; m < 4; ++m)
#pragma unroll
    for(int n = 0; n < 2; ++n) acc[m][n] = (f32x4){0.f, 0.f, 0.f, 0.f};

  auto STAGE = [&](int kt){
    const int e = kt % 9, ci0 = (kt / 9) << 6;   // ci-major
    const int dy = e / 3 - 1, dx = e % 3 - 1;
    const int aD = (dy * PROW + dx) * 512 + ci0;
    const u32 bD = (u32)e * 256u * 512u + ci0;
    u16* bufA = &lds[kt & 1][0];
    u16* bufB = &lds[kt & 1][8192];
#pragma unroll
    for(int j = 0; j < 2; ++j){
      const int c = w * 2 + j;
      gl16(A + aB[j] + aD, bufA + c * 512);
      gl16(W + bB[j] + bD, bufB + c * 512);
    }
  };

  STAGE(0);
  STAGE(1);

  for(int t = 0; t < NT; ++t){
    if(t < NT - 1) asm volatile("s_waitcnt vmcnt(4)" ::: "memory");
    else           asm volatile("s_waitcnt vmcnt(0)" ::: "memory");
    __builtin_amdgcn_s_barrier();
    const char* bufA = (const char*)&lds[t & 1][0];
    const char* bufB = bufA + 16384;
    bf16x8 af[4][2], bq[2][2];
#pragma unroll
    for(int m = 0; m < 4; ++m){
      const int row = wr * 64 + m * 16 + l15;
      const int sz = (row & 7) << 4;
#pragma unroll
      for(int kk = 0; kk < 2; ++kk)
        af[m][kk] = *(const bf16x8*)(bufA + row * 128 + (((kk * 4 + lq) * 16) ^ sz));
    }
#pragma unroll
    for(int n = 0; n < 2; ++n){
      const int row = wc * 32 + n * 16 + l15;
      const int sz = (row & 7) << 4;
#pragma unroll
      for(int kk = 0; kk < 2; ++kk)
        bq[n][kk] = *(const bf16x8*)(bufB + row * 128 + (((kk * 4 + lq) * 16) ^ sz));
    }
    asm volatile("s_waitcnt lgkmcnt(0)" ::: "memory");
    __builtin_amdgcn_sched_barrier(0);
    __builtin_amdgcn_s_barrier();
    if(t + 2 < NT) STAGE(t + 2);
    __builtin_amdgcn_s_setprio(1);
#pragma unroll
    for(int kk = 0; kk < 2; ++kk)
#pragma unroll
      for(int m = 0; m < 4; ++m)
#pragma unroll
        for(int n = 0; n < 2; ++n)
          MFMA16(acc[m][n], af[m][kk], bq[n][kk]);
    __builtin_amdgcn_s_setprio(0);
  }

#pragma unroll
  for(int m = 0; m < 4; ++m){
    const int p0 = m0 + wr * 64 + m * 16 + lq * 4;
    const size_t pp = ((size_t)b * PIMG + (size_t)((p0 >> 7) + 1) * PROW + (p0 & 127) + 1) * 512;
#pragma unroll
    for(int n = 0; n < 2; ++n){
      const int co = n0 + wc * 32 + n * 16 + l15;
      const float bi = bias[co];
#pragma unroll
      for(int r = 0; r < 4; ++r){
        float v = acc[m][n][r] + bi;
        v = v > 0.f ? v : 0.2f * v;
        FUSEDP[pp + (size_t)r * 512 + 256 + co] = f2bf(v);
      }
    }
  }
}

// ---------------------------------------------------------------------------
// conv<1> (gate/feat fused): 16-wave block, BM=BN=256, BK=64 (128B rows,
// 0-conflict swizzle), 4 waves/SIMD, 2-barrier loop + counted vmcnt(4),
// ci-major K-order; per-kk fragment reload keeps VGPR < 128.
__global__ __launch_bounds__(1024, 4) void k_convB16(const u16* __restrict__ A,
                                                     const u16* __restrict__ W,
                                                     const float* __restrict__ bias,
                                                     const float* __restrict__ bias2,
                                                     float* __restrict__ out){
  constexpr int NT = 72;
  __shared__ u16 lds[2][32768];                  // A [256][64] @0, B @16384 (u16)
  const int id = blockIdx.x;                     // 256 blocks
  const int wg = (id & 7) * 32 + (id >> 3);      // XCD-contiguous (256 = 8*32)
  const int ntile = wg >> 7;
  const int rem = wg & 127, b = rem >> 6, mt = rem & 63;
  const int m0 = mt * 256, n0 = ntile * 256;
  const int tid = threadIdx.x, w = tid >> 6, l = tid & 63;
  const int wr = w >> 2, wc = w & 3;             // 4 x 4 waves -> per-wave 64x64
  const int l15 = l & 15, lq = l >> 4;
  const int lr = l >> 3;
  const u32 laneswz = (u32)((((l & 7) * 16) ^ (lr << 4)) >> 1);

  u32 aB[2], bB[2];
#pragma unroll
  for(int j = 0; j < 2; ++j){
    const int row = (w * 2 + j) * 8 + lr;        // 32 chunks of 8 rows
    const int p = m0 + row;
    aB[j] = ((u32)b * PIMG + ((u32)(p >> 7) + 1) * PROW + (u32)(p & 127) + 1) * 512 + laneswz;
    bB[j] = (u32)(n0 + row) * 512 + laneswz;
  }

  f32x4 acc[4][4];
#pragma unroll
  for(int m = 0; m < 4; ++m)
#pragma unroll
    for(int n = 0; n < 4; ++n) acc[m][n] = (f32x4){0.f, 0.f, 0.f, 0.f};

  auto STAGE = [&](int kt){
    const int e = kt % 9, ci0 = (kt / 9) << 6;   // ci-major
    const int dy = e / 3 - 1, dx = e % 3 - 1;
    const int aD = (dy * PROW + dx) * 512 + ci0;
    const u32 bD = (u32)e * 512u * 512u + ci0;
    u16* bufA = &lds[kt & 1][0];
    u16* bufB = &lds[kt & 1][16384];
#pragma unroll
    for(int j = 0; j < 2; ++j){
      const int c = w * 2 + j;
      gl16(A + aB[j] + aD, bufA + c * 512);
      gl16(W + bB[j] + bD, bufB + c * 512);
    }
  };

  STAGE(0);
  STAGE(1);

  for(int t = 0; t < NT; ++t){
    if(t < NT - 1) asm volatile("s_waitcnt vmcnt(4)" ::: "memory");
    else           asm volatile("s_waitcnt vmcnt(0)" ::: "memory");
    __builtin_amdgcn_s_barrier();                  // buf[t&1] data visible
    const char* bufA = (const char*)&lds[t & 1][0];
    const char* bufB = bufA + 32768;
    bf16x8 af[4], bq[4];
    // ---- kk = 0: read 8 frags, drain, MFMA 16 (overlaps kk=1 read issue)
#pragma unroll
    for(int m = 0; m < 4; ++m){
      const int row = wr * 64 + m * 16 + l15;
      af[m] = *(const bf16x8*)(bufA + row * 128 + ((lq * 16) ^ ((row & 7) << 4)));
    }
#pragma unroll
    for(int n = 0; n < 4; ++n){
      const int row = wc * 64 + n * 16 + l15;
      bq[n] = *(const bf16x8*)(bufB + row * 128 + ((lq * 16) ^ ((row & 7) << 4)));
    }
    asm volatile("s_waitcnt lgkmcnt(0)" ::: "memory");
    __builtin_amdgcn_sched_barrier(0);
    __builtin_amdgcn_s_setprio(1);
#pragma unroll
    for(int m = 0; m < 4; ++m)
#pragma unroll
      for(int n = 0; n < 4; ++n)
        MFMA16(acc[m][n], af[m], bq[n]);
    __builtin_amdgcn_s_setprio(0);
    // ---- kk = 1: reuse frag registers
#pragma unroll
    for(int m = 0; m < 4; ++m){
      const int row = wr * 64 + m * 16 + l15;
      af[m] = *(const bf16x8*)(bufA + row * 128 + ((64 + lq * 16) ^ ((row & 7) << 4)));
    }
#pragma unroll
    for(int n = 0; n < 4; ++n){
      const int row = wc * 64 + n * 16 + l15;
      bq[n] = *(const bf16x8*)(bufB + row * 128 + ((64 + lq * 16) ^ ((row & 7) << 4)));
    }
    asm volatile("s_waitcnt lgkmcnt(0)" ::: "memory");
    __builtin_amdgcn_sched_barrier(0);
    __builtin_amdgcn_s_barrier();                  // all reads of buf[t&1] done
    if(t + 2 < NT) STAGE(t + 2);                   // refill just-freed buffer
    __builtin_amdgcn_s_setprio(1);
#pragma unroll
    for(int m = 0; m < 4; ++m)
#pragma unroll
      for(int n = 0; n < 4; ++n)
        MFMA16(acc[m][n], af[m], bq[n]);
    __builtin_amdgcn_s_setprio(0);
  }

#pragma unroll
  for(int m = 0; m < 4; ++m){
    const int p0 = m0 + wr * 64 + m * 16 + lq * 4;
#pragma unroll
    for(int n = 0; n < 4; ++n){
      const int col = n0 + wc * 64 + n * 16 + l15;
      const int s = col & 1, co = col >> 1;
      const float big = bias[co], bif = bias2[co];
      float res[4];
#pragma unroll
      for(int r = 0; r < 4; ++r){
        const float val = acc[m][n][r];
        const float oth = __shfl_xor(val, 1);
        float gg = s ? oth : val;
        float ff = s ? val : oth;
        gg += big; ff += bif;
        ff = ff > 0.f ? ff : 0.2f * ff;
        res[r] = ff / (1.0f + __expf(-gg));
      }
      if(s == 0){
        float4 v4 = make_float4(res[0], res[1], res[2], res[3]);
        *(float4*)&out[((size_t)b * 256 + co) * 16384 + p0] = v4;
      }
    }
  }
}

// ---------------------------------------------------------------------------
extern "C" void kernel_launch(void* const* d_in, const int* in_sizes, int n_in,
                              void* d_out, int out_size, void* d_ws, size_t ws_size,
                              hipStream_t stream){
  const float* x      = (const float*)d_in[0];
  const float* xs     = (const float*)d_in[1];
  // d_in[2] = ms : unused (mask is a no-op in the reference)
  const float* w_lin  = (const float*)d_in[3];
  const float* b_lin  = (const float*)d_in[4];
  const float* w_gate = (const float*)d_in[5];
  const float* b_gate = (const float*)d_in[6];
  const float* w_feat = (const float*)d_in[7];
  const float* b_feat = (const float*)d_in[8];
  float* out = (float*)d_out;

  char* ws = (char*)d_ws;
  size_t off = 0;
  auto alloc = [&](size_t bytes) -> void* {
    void* p = ws + off;
    off += (bytes + 255) & ~(size_t)255;
    return p;
  };
  u16* FUSEDP  = (u16*)alloc(2ull * PIMGC * 2);       // padded [b][130][130][512]
  u16* OUTCATP = (u16*)alloc(2ull * PIMGC * 2);       // padded [b][130][130][512]
  u16* XST     = (u16*)alloc(10ull * 16384 * 256 * 2);// xs NHWC bf16
  u16* WTl     = (u16*)alloc(9ull * 256 * 512 * 2);   // [e][co][ci]
  u16* WGF     = (u16*)alloc(9ull * 512 * 512 * 2);   // [e][2co+s][ci]
  float* S8p   = (float*)alloc(8ull * 655360 * 4);    // [g][b][256][1280]
  u16* A8      = (u16*)alloc(655360ull * 2);          // bf16 [b][256][1280]
  u16* A16     = (u16*)alloc(2ull * 64 * 320 * 2);    // bf16 [b][64][320]

  // zero padded borders (interior written by producers)
  k_border<<<dim3(129, 2), 256, 0, stream>>>(FUSEDP);
  k_border<<<dim3(129, 2), 256, 0, stream>>>(OUTCATP);

  dim3 tb(32, 8);
  k_transPadW<<<dim3(4, 512, 2), tb, 0, stream>>>(x, FUSEDP);
  k_transW<<<dim3(4, 512, 10), tb, 0, stream>>>(xs, XST, 16384, 256, 4194304ull);

  k_wt2<<<256, 512, 0, stream>>>(w_lin,  WTl, 1, 0, 256);
  k_wt2<<<256, 512, 0, stream>>>(w_gate, WGF, 2, 0, 512);
  k_wt2<<<256, 512, 0, stream>>>(w_feat, WGF, 2, 1, 512);

  k_scores8<<<dim3(2, 10, 16), 512, 0, stream>>>(FUSEDP, XST, S8p);
  k_softmax8<<<512, 256, 0, stream>>>(S8p, A8);
  k_s16<<<128, 320, 0, stream>>>(S8p, A16);

  k_val8 <<<dim3(2, 2, 128), 256, 0, stream>>>(A8, XST, OUTCATP);
  k_val16<<<dim3(1, 2, 512), 256, 0, stream>>>(A16, XST, OUTCATP);

  k_convA<<<512, 512, 0, stream>>>(OUTCATP, WTl, b_lin, FUSEDP);
  k_convB16<<<256, 1024, 0, stream>>>(FUSEDP, WGF, b_gate, b_feat, out);
}